// Round 1
// baseline (1538.487 us; speedup 1.0000x reference)
//
#include <hip/hip_runtime.h>
#include <hip/hip_bf16.h>

#define NN   20000
#define EE   320000
#define GG   16
#define DD   256
#define HH   8
#define DHH  32
#define LLAYERS 2
#define DFF  512
#define DIN  32
#define DLAP 16

// ---------------------------------------------------------------- embed
__global__ __launch_bounds__(256) void k_embed(
    const float* __restrict__ feat, const float* __restrict__ lap,
    const float* __restrict__ sign, const float* __restrict__ Wh,
    const float* __restrict__ bh, const float* __restrict__ Wlp,
    const float* __restrict__ blp, float* __restrict__ h) {
  int n = blockIdx.x;
  int d = threadIdx.x;
  float acc = bh[d] + blp[d];
  const float* frow = feat + (size_t)n * DIN;
  const float* lrow = lap + (size_t)n * DLAP;
#pragma unroll
  for (int k = 0; k < DIN; ++k) acc += frow[k] * Wh[k * DD + d];
#pragma unroll
  for (int k = 0; k < DLAP; ++k) acc += (lrow[k] * sign[k]) * Wlp[k * DD + d];
  h[(size_t)n * DD + d] = acc;
}

// ---------------------------------------------------------------- tiled f32 GEMM
// C[M,Ncols] = A[M,K] @ B[K,Ncols] (+bias, +relu). BM=BN=64, BK=16, 256 thr, 4x4 micro.
template <bool BIAS, bool RELU>
__global__ __launch_bounds__(256) void gemm_f32(
    const float* __restrict__ A, const float* __restrict__ B,
    const float* __restrict__ bias, float* __restrict__ C,
    int M, int Ncols, int K) {
  __shared__ float As[16][68];  // transposed: As[k][row]
  __shared__ float Bs[16][68];  // Bs[k][col]
  const int t = threadIdx.x;
  const int bm = blockIdx.x * 64;
  const int bn = blockIdx.y * 64;
  const int tx = t & 15, ty = t >> 4;
  const int arow = t >> 2;
  const int ak4 = (t & 3) * 4;
  const int brow = t >> 4;
  const int bc4 = (t & 15) * 4;
  float acc[4][4] = {};
  const int ntiles = K >> 4;
  for (int kt = 0; kt < ntiles; ++kt) {
    const int k0 = kt << 4;
    float4 av = make_float4(0.f, 0.f, 0.f, 0.f);
    if (bm + arow < M)
      av = *(const float4*)(A + (size_t)(bm + arow) * K + k0 + ak4);
    float4 bv = *(const float4*)(B + (size_t)(k0 + brow) * Ncols + bn + bc4);
    As[ak4 + 0][arow] = av.x;
    As[ak4 + 1][arow] = av.y;
    As[ak4 + 2][arow] = av.z;
    As[ak4 + 3][arow] = av.w;
    Bs[brow][bc4 + 0] = bv.x;
    Bs[brow][bc4 + 1] = bv.y;
    Bs[brow][bc4 + 2] = bv.z;
    Bs[brow][bc4 + 3] = bv.w;
    __syncthreads();
#pragma unroll
    for (int kk = 0; kk < 16; ++kk) {
      float4 a4 = *(const float4*)&As[kk][ty * 4];
      float4 b4 = *(const float4*)&Bs[kk][tx * 4];
      acc[0][0] += a4.x * b4.x; acc[0][1] += a4.x * b4.y;
      acc[0][2] += a4.x * b4.z; acc[0][3] += a4.x * b4.w;
      acc[1][0] += a4.y * b4.x; acc[1][1] += a4.y * b4.y;
      acc[1][2] += a4.y * b4.z; acc[1][3] += a4.y * b4.w;
      acc[2][0] += a4.z * b4.x; acc[2][1] += a4.z * b4.y;
      acc[2][2] += a4.z * b4.z; acc[2][3] += a4.z * b4.w;
      acc[3][0] += a4.w * b4.x; acc[3][1] += a4.w * b4.y;
      acc[3][2] += a4.w * b4.z; acc[3][3] += a4.w * b4.w;
    }
    __syncthreads();
  }
#pragma unroll
  for (int i = 0; i < 4; ++i) {
    int row = bm + ty * 4 + i;
    if (row >= M) continue;
    float4 ov;
    float* op = &ov.x;
#pragma unroll
    for (int j = 0; j < 4; ++j) {
      float v = acc[i][j];
      if (BIAS) v += bias[bn + tx * 4 + j];
      if (RELU) v = fmaxf(v, 0.f);
      op[j] = v;
    }
    *(float4*)(C + (size_t)row * Ncols + bn + tx * 4) = ov;
  }
}

// ---------------------------------------------------------------- CSR build
__global__ void k_hist(const int* __restrict__ dst, int* __restrict__ deg, int n) {
  int i = blockIdx.x * blockDim.x + threadIdx.x;
  if (i < n) atomicAdd(&deg[dst[i]], 1);
}

__global__ __launch_bounds__(256) void k_scan_block(
    const int* __restrict__ in, int* __restrict__ ex, int* __restrict__ bsum, int n) {
  __shared__ int sm[256];
  int t = threadIdx.x;
  int i = blockIdx.x * 256 + t;
  int v = (i < n) ? in[i] : 0;
  sm[t] = v;
  __syncthreads();
  for (int o = 1; o < 256; o <<= 1) {
    int x = (t >= o) ? sm[t - o] : 0;
    __syncthreads();
    sm[t] += x;
    __syncthreads();
  }
  if (i < n) ex[i] = sm[t] - v;
  if (t == 255) bsum[blockIdx.x] = sm[255];
}

__global__ __launch_bounds__(256) void k_scan_top(
    const int* __restrict__ bsum, int* __restrict__ boff, int nb) {
  __shared__ int sm[256];
  int t = threadIdx.x;
  int v = (t < nb) ? bsum[t] : 0;
  sm[t] = v;
  __syncthreads();
  for (int o = 1; o < 256; o <<= 1) {
    int x = (t >= o) ? sm[t - o] : 0;
    __syncthreads();
    sm[t] += x;
    __syncthreads();
  }
  if (t < nb) boff[t] = sm[t] - v;
}

__global__ void k_finish_indptr(const int* __restrict__ ex, const int* __restrict__ boff,
                                int* __restrict__ indptr, int* __restrict__ cursor,
                                int n, int total) {
  int i = blockIdx.x * 256 + threadIdx.x;
  if (i < n) {
    int v = ex[i] + boff[i >> 8];
    indptr[i] = v;
    cursor[i] = v;
  }
  if (i == 0) indptr[n] = total;
}

__global__ void k_fill(const int* __restrict__ dst, int* __restrict__ cursor,
                       int* __restrict__ indices, int n) {
  int i = blockIdx.x * blockDim.x + threadIdx.x;
  if (i < n) {
    int pos = atomicAdd(&cursor[dst[i]], 1);
    indices[pos] = i;
  }
}

// ---------------------------------------------------------------- edge scores
// s[e,h] = exp(clip(dot(K[src],Q[dst])/sqrt(32), -5, 5))
__global__ __launch_bounds__(256) void k_edge_score(
    const float* __restrict__ Q, const float* __restrict__ Kb,
    const int* __restrict__ src, const int* __restrict__ dst,
    float* __restrict__ sedge, int ne) {
  int idx = blockIdx.x * blockDim.x + threadIdx.x;
  if (idx >= ne * HH) return;
  int e = idx >> 3;
  int hh = idx & 7;
  const float* kr = Kb + (size_t)src[e] * DD + hh * DHH;
  const float* qr = Q + (size_t)dst[e] * DD + hh * DHH;
  float dot = 0.f;
#pragma unroll
  for (int d = 0; d < DHH; ++d) dot += kr[d] * qr[d];
  float x = dot * 0.17677669529663687f;  // 1/sqrt(32)
  x = fminf(fmaxf(x, -5.f), 5.f);
  sedge[idx] = expf(x);
}

// ---------------------------------------------------------------- segment softmax + p*V aggregation
// one block per node; 8 groups of 32 lanes = (head, dim)
__global__ __launch_bounds__(256) void k_aggregate(
    const int* __restrict__ indptr, const int* __restrict__ indices,
    const int* __restrict__ src, const float* __restrict__ sedge,
    const float* __restrict__ V, float* __restrict__ attn) {
  int n = blockIdx.x;
  int t = threadIdx.x;
  int hh = t >> 5, lane = t & 31;
  int s0 = indptr[n], s1 = indptr[n + 1];
  float m = 0.f;  // all s > 0, so 0 is a safe identity for non-empty segments
  for (int i = s0 + lane; i < s1; i += 32)
    m = fmaxf(m, sedge[(size_t)indices[i] * HH + hh]);
#pragma unroll
  for (int o = 16; o > 0; o >>= 1) m = fmaxf(m, __shfl_xor(m, o, 32));
  float den = 0.f, acc = 0.f;
  for (int i = s0; i < s1; ++i) {
    int e = indices[i];
    float p = expf(sedge[(size_t)e * HH + hh] - m);
    den += p;
    acc += p * V[(size_t)src[e] * DD + hh * DHH + lane];
  }
  attn[(size_t)n * DD + hh * DHH + lane] = acc / (den > 0.f ? den : 1.f);
}

// ---------------------------------------------------------------- residual + LayerNorm (in-place on h)
__global__ __launch_bounds__(256) void k_ln(
    float* __restrict__ h, const float* __restrict__ add,
    const float* __restrict__ g, const float* __restrict__ b, int n) {
  int row = blockIdx.x * 4 + (threadIdx.x >> 6);
  int lane = threadIdx.x & 63;
  if (row >= n) return;
  const size_t base = (size_t)row * DD;
  float x[4];
  float s = 0.f;
#pragma unroll
  for (int j = 0; j < 4; ++j) {
    int d = lane + j * 64;
    x[j] = h[base + d] + add[base + d];
    s += x[j];
  }
#pragma unroll
  for (int o = 32; o > 0; o >>= 1) s += __shfl_xor(s, o, 64);
  float mean = s * (1.f / 256.f);
  float vs = 0.f;
#pragma unroll
  for (int j = 0; j < 4; ++j) {
    float d = x[j] - mean;
    vs += d * d;
  }
#pragma unroll
  for (int o = 32; o > 0; o >>= 1) vs += __shfl_xor(vs, o, 64);
  float rs = rsqrtf(vs * (1.f / 256.f) + 1e-5f);
#pragma unroll
  for (int j = 0; j < 4; ++j) {
    int d = lane + j * 64;
    h[base + d] = g[d] * ((x[j] - mean) * rs) + b[d];
  }
}

// ---------------------------------------------------------------- readout
__global__ void k_counts(const int* __restrict__ gid, int* __restrict__ gcnt, int n) {
  int i = blockIdx.x * blockDim.x + threadIdx.x;
  if (i < n) atomicAdd(&gcnt[gid[i]], 1);
}

__global__ __launch_bounds__(256) void k_gsum(
    const float* __restrict__ h, const int* __restrict__ gid,
    float* __restrict__ gsum, int n) {
  __shared__ float bins[GG * DD];
  int t = threadIdx.x;
  for (int i = t; i < GG * DD; i += 256) bins[i] = 0.f;
  __syncthreads();
  for (int nn = blockIdx.x; nn < n; nn += gridDim.x) {
    int g = gid[nn];
    bins[g * DD + t] += h[(size_t)nn * DD + t];  // thread t owns column t
  }
  __syncthreads();
  for (int i = t; i < GG * DD; i += 256) atomicAdd(&gsum[i], bins[i]);
}

__global__ void k_final(const float* __restrict__ gsum, const int* __restrict__ gcnt,
                        float* __restrict__ out) {
  int g = blockIdx.x, t = threadIdx.x;
  int c = gcnt[g];
  out[g * DD + t] = gsum[g * DD + t] / (c > 0 ? (float)c : 1.f);
}

// ---------------------------------------------------------------- launch
extern "C" void kernel_launch(void* const* d_in, const int* in_sizes, int n_in,
                              void* d_out, int out_size, void* d_ws, size_t ws_size,
                              hipStream_t stream) {
  const float* feat = (const float*)d_in[0];
  const float* lap  = (const float*)d_in[1];
  const float* sign = (const float*)d_in[2];
  const int* srcs   = (const int*)d_in[3];
  const int* dsts   = (const int*)d_in[4];
  const int* gids   = (const int*)d_in[5];
  const float* Wh   = (const float*)d_in[6];
  const float* bh   = (const float*)d_in[7];
  const float* Wlp  = (const float*)d_in[8];
  const float* blp  = (const float*)d_in[9];
  const float* Wq   = (const float*)d_in[10];
  const float* Wk   = (const float*)d_in[11];
  const float* Wv   = (const float*)d_in[12];
  const float* Wo   = (const float*)d_in[13];
  const float* bo   = (const float*)d_in[14];
  const float* g1   = (const float*)d_in[15];
  const float* b1   = (const float*)d_in[16];
  const float* W1   = (const float*)d_in[17];
  const float* c1   = (const float*)d_in[18];
  const float* W2   = (const float*)d_in[19];
  const float* c2   = (const float*)d_in[20];
  const float* g2   = (const float*)d_in[21];
  const float* b2   = (const float*)d_in[22];

  char* base = (char*)d_ws;
  size_t off = 0;
  auto take = [&](size_t bytes) -> void* {
    void* p = base + off;
    off += (bytes + 255) & ~(size_t)255;
    return p;
  };
  float* h     = (float*)take((size_t)NN * DD * 4);
  float* Qb    = (float*)take((size_t)NN * DD * 4);
  float* Kb    = (float*)take((size_t)NN * DD * 4);
  float* Vb    = (float*)take((size_t)NN * DD * 4);
  float* sedge = (float*)take((size_t)EE * HH * 4);
  float* t1    = (float*)take((size_t)NN * DFF * 4);
  int* deg     = (int*)take((size_t)NN * 4);
  int* ex      = (int*)take((size_t)NN * 4);
  int* bsum    = (int*)take(256 * 4);
  int* boff    = (int*)take(256 * 4);
  int* indptr  = (int*)take((size_t)(NN + 1) * 4);
  int* cursor  = (int*)take((size_t)NN * 4);
  int* indices = (int*)take((size_t)EE * 4);
  float* gsum  = (float*)take((size_t)GG * DD * 4);
  int* gcnt    = (int*)take((size_t)GG * 4);
  float* attnb = Qb;  // reuse: Q dead after edge scores
  float* tmp   = Kb;  // reuse: K dead after edge scores

  const int NB = (NN + 255) / 256;  // 79

  // CSR by dst (rebuilt every call; dst is constant input)
  hipMemsetAsync(deg, 0, (size_t)NN * 4, stream);
  k_hist<<<(EE + 255) / 256, 256, 0, stream>>>(dsts, deg, EE);
  k_scan_block<<<NB, 256, 0, stream>>>(deg, ex, bsum, NN);
  k_scan_top<<<1, 256, 0, stream>>>(bsum, boff, NB);
  k_finish_indptr<<<NB, 256, 0, stream>>>(ex, boff, indptr, cursor, NN, EE);
  k_fill<<<(EE + 255) / 256, 256, 0, stream>>>(dsts, cursor, indices, EE);

  // input embedding
  k_embed<<<NN, 256, 0, stream>>>(feat, lap, sign, Wh, bh, Wlp, blp, h);

  dim3 gD((NN + 63) / 64, DD / 64);
  dim3 gF((NN + 63) / 64, DFF / 64);

  for (int l = 0; l < LLAYERS; ++l) {
    const float* Wq_l = Wq + (size_t)l * DD * DD;
    const float* Wk_l = Wk + (size_t)l * DD * DD;
    const float* Wv_l = Wv + (size_t)l * DD * DD;
    const float* Wo_l = Wo + (size_t)l * DD * DD;
    const float* bo_l = bo + (size_t)l * DD;
    const float* g1_l = g1 + (size_t)l * DD;
    const float* b1_l = b1 + (size_t)l * DD;
    const float* W1_l = W1 + (size_t)l * DD * DFF;
    const float* c1_l = c1 + (size_t)l * DFF;
    const float* W2_l = W2 + (size_t)l * DFF * DD;
    const float* c2_l = c2 + (size_t)l * DD;
    const float* g2_l = g2 + (size_t)l * DD;
    const float* b2_l = b2 + (size_t)l * DD;

    gemm_f32<false, false><<<gD, 256, 0, stream>>>(h, Wq_l, nullptr, Qb, NN, DD, DD);
    gemm_f32<false, false><<<gD, 256, 0, stream>>>(h, Wk_l, nullptr, Kb, NN, DD, DD);
    gemm_f32<false, false><<<gD, 256, 0, stream>>>(h, Wv_l, nullptr, Vb, NN, DD, DD);

    k_edge_score<<<((size_t)EE * HH + 255) / 256, 256, 0, stream>>>(Qb, Kb, srcs, dsts, sedge, EE);
    k_aggregate<<<NN, 256, 0, stream>>>(indptr, indices, srcs, sedge, Vb, attnb);

    gemm_f32<true, false><<<gD, 256, 0, stream>>>(attnb, Wo_l, bo_l, tmp, NN, DD, DD);
    k_ln<<<NN / 4, 256, 0, stream>>>(h, tmp, g1_l, b1_l, NN);

    gemm_f32<true, true><<<gF, 256, 0, stream>>>(h, W1_l, c1_l, t1, NN, DFF, DD);
    gemm_f32<true, false><<<gD, 256, 0, stream>>>(t1, W2_l, c2_l, tmp, NN, DD, DFF);
    k_ln<<<NN / 4, 256, 0, stream>>>(h, tmp, g2_l, b2_l, NN);
  }

  hipMemsetAsync(gsum, 0, (size_t)GG * DD * 4, stream);
  hipMemsetAsync(gcnt, 0, (size_t)GG * 4, stream);
  k_counts<<<NB, 256, 0, stream>>>(gids, gcnt, NN);
  k_gsum<<<64, 256, 0, stream>>>(h, gids, gsum, NN);
  k_final<<<GG, 256, 0, stream>>>(gsum, gcnt, (float*)d_out);
}

// Round 2
// 907.736 us; speedup vs baseline: 1.6949x; 1.6949x over previous
//
#include <hip/hip_runtime.h>
#include <hip/hip_bf16.h>

#define NN   20000
#define EE   320000
#define GG   16
#define DD   256
#define HH   8
#define DHH  32
#define LLAYERS 2
#define DFF  512
#define DIN  32
#define DLAP 16

typedef __attribute__((ext_vector_type(8))) short bf16x8;
typedef __attribute__((ext_vector_type(4))) float f32x4;

__device__ __forceinline__ void gld_lds16(const void* g, void* l) {
  __builtin_amdgcn_global_load_lds((const __attribute__((address_space(1))) uint32_t*)g,
                                   (__attribute__((address_space(3))) uint32_t*)l, 16, 0, 0);
}

// ---------------------------------------------------------------- embed (f32 + bf16 shadow)
__global__ __launch_bounds__(256) void k_embed(
    const float* __restrict__ feat, const float* __restrict__ lap,
    const float* __restrict__ sign, const float* __restrict__ Wh,
    const float* __restrict__ bh, const float* __restrict__ Wlp,
    const float* __restrict__ blp, float* __restrict__ h,
    __hip_bfloat16* __restrict__ hb) {
  int n = blockIdx.x;
  int d = threadIdx.x;
  float acc = bh[d] + blp[d];
  const float* frow = feat + (size_t)n * DIN;
  const float* lrow = lap + (size_t)n * DLAP;
#pragma unroll
  for (int k = 0; k < DIN; ++k) acc += frow[k] * Wh[k * DD + d];
#pragma unroll
  for (int k = 0; k < DLAP; ++k) acc += (lrow[k] * sign[k]) * Wlp[k * DD + d];
  h[(size_t)n * DD + d] = acc;
  hb[(size_t)n * DD + d] = __float2bfloat16(acc);
}

// ---------------------------------------------------------------- weight transpose+convert
// in: [L][K][N] f32 (layer via blockIdx.z), out: [L][N][K] bf16
__global__ __launch_bounds__(256) void k_wt(
    const float* __restrict__ in, __hip_bfloat16* __restrict__ out, int K, int N) {
  __shared__ float tile[32][33];
  const float* inl = in + (size_t)blockIdx.z * K * N;
  __hip_bfloat16* outl = out + (size_t)blockIdx.z * N * K;
  int bx = blockIdx.x;  // N tiles
  int by = blockIdx.y;  // K tiles
  int tx = threadIdx.x & 31, ty = threadIdx.x >> 5;
#pragma unroll
  for (int i = 0; i < 32; i += 8)
    tile[ty + i][tx] = inl[(size_t)(by * 32 + ty + i) * N + bx * 32 + tx];
  __syncthreads();
#pragma unroll
  for (int i = 0; i < 32; i += 8)
    outl[(size_t)(bx * 32 + ty + i) * K + by * 32 + tx] = __float2bfloat16(tile[tx][ty + i]);
}

// ---------------------------------------------------------------- MFMA bf16 GEMM
// C = A[M][K] @ B[K][N], B given transposed: Bt[N][K]. 128x128 tile, BK=32,
// 256 thr = 4 waves (2x2), each wave 64x64 = 4x4 frags of 16x16x32.
// grid.z selects among up to 3 (Bt,C) pairs (batched QKV).
template <bool BIAS, bool RELU, bool OUTBF16>
__global__ __launch_bounds__(256) void gemm_mfma(
    const __hip_bfloat16* __restrict__ A,
    const __hip_bfloat16* __restrict__ Bt0, const __hip_bfloat16* __restrict__ Bt1,
    const __hip_bfloat16* __restrict__ Bt2,
    const float* __restrict__ bias,
    void* __restrict__ C0, void* __restrict__ C1, void* __restrict__ C2,
    int M, int Ncols, int K) {
  const __hip_bfloat16* Bt = (blockIdx.z == 0) ? Bt0 : (blockIdx.z == 1) ? Bt1 : Bt2;
  void* Cout = (blockIdx.z == 0) ? C0 : (blockIdx.z == 1) ? C1 : C2;

  // LDS layout: l[buf][g][row][8 bf16]; frag (g=lane>>4) reads are 16B-contiguous
  __shared__ short lA[2][4][128][8];
  __shared__ short lB[2][4][128][8];

  const int t = threadIdx.x;
  const int lane = t & 63, w = t >> 6;
  const int bm = blockIdx.x * 128, bn = blockIdx.y * 128;
  const int wr = w >> 1, wc = w & 1;
  const int fr = lane & 15, fg = lane >> 4;

  f32x4 acc[4][4] = {};

  auto stage = [&](int buf, int kt) {
    const int k0 = kt * 32;
#pragma unroll
    for (int it = 0; it < 2; ++it) {
      const int cbase = it * 256 + w * 64;      // wave-uniform chunk base
      const int c = cbase + lane;               // this lane's chunk
      const int g = c >> 7, r = c & 127;
      int arow = bm + r;
      if (arow >= M) arow = M - 1;
      gld_lds16(A + (size_t)arow * K + k0 + g * 8,
                (short*)lA + ((size_t)buf * 4 * 128 + cbase) * 8);
      gld_lds16(Bt + (size_t)(bn + r) * K + k0 + g * 8,
                (short*)lB + ((size_t)buf * 4 * 128 + cbase) * 8);
    }
  };

  const int nt = K >> 5;
  stage(0, 0);
  for (int kt = 0; kt < nt; ++kt) {
    const int buf = kt & 1;
    __syncthreads();  // drains vmcnt: stage(buf) complete; prior reads of buf^1 done
    if (kt + 1 < nt) stage(buf ^ 1, kt + 1);
    bf16x8 af[4], bfr[4];
#pragma unroll
    for (int i = 0; i < 4; ++i)
      af[i] = *(const bf16x8*)&lA[buf][fg][wr * 64 + i * 16 + fr][0];
#pragma unroll
    for (int j = 0; j < 4; ++j)
      bfr[j] = *(const bf16x8*)&lB[buf][fg][wc * 64 + j * 16 + fr][0];
#pragma unroll
    for (int i = 0; i < 4; ++i)
#pragma unroll
      for (int j = 0; j < 4; ++j)
        acc[i][j] = __builtin_amdgcn_mfma_f32_16x16x32_bf16(af[i], bfr[j], acc[i][j], 0, 0, 0);
  }

#pragma unroll
  for (int i = 0; i < 4; ++i) {
    const int row0 = bm + wr * 64 + i * 16 + fg * 4;
#pragma unroll
    for (int j = 0; j < 4; ++j) {
      const int col = bn + wc * 64 + j * 16 + fr;
      float bv = BIAS ? bias[col] : 0.f;
#pragma unroll
      for (int r = 0; r < 4; ++r) {
        const int row = row0 + r;
        if (row >= M) continue;
        float v = acc[i][j][r] + bv;
        if (RELU) v = fmaxf(v, 0.f);
        if (OUTBF16)
          ((__hip_bfloat16*)Cout)[(size_t)row * Ncols + col] = __float2bfloat16(v);
        else
          ((float*)Cout)[(size_t)row * Ncols + col] = v;
      }
    }
  }
}

// ---------------------------------------------------------------- CSR build
__global__ void k_hist(const int* __restrict__ dst, int* __restrict__ deg, int n) {
  int i = blockIdx.x * blockDim.x + threadIdx.x;
  if (i < n) atomicAdd(&deg[dst[i]], 1);
}

__global__ __launch_bounds__(256) void k_scan_block(
    const int* __restrict__ in, int* __restrict__ ex, int* __restrict__ bsum, int n) {
  __shared__ int sm[256];
  int t = threadIdx.x;
  int i = blockIdx.x * 256 + t;
  int v = (i < n) ? in[i] : 0;
  sm[t] = v;
  __syncthreads();
  for (int o = 1; o < 256; o <<= 1) {
    int x = (t >= o) ? sm[t - o] : 0;
    __syncthreads();
    sm[t] += x;
    __syncthreads();
  }
  if (i < n) ex[i] = sm[t] - v;
  if (t == 255) bsum[blockIdx.x] = sm[255];
}

__global__ __launch_bounds__(256) void k_scan_top(
    const int* __restrict__ bsum, int* __restrict__ boff, int nb) {
  __shared__ int sm[256];
  int t = threadIdx.x;
  int v = (t < nb) ? bsum[t] : 0;
  sm[t] = v;
  __syncthreads();
  for (int o = 1; o < 256; o <<= 1) {
    int x = (t >= o) ? sm[t - o] : 0;
    __syncthreads();
    sm[t] += x;
    __syncthreads();
  }
  if (t < nb) boff[t] = sm[t] - v;
}

__global__ void k_finish_indptr(const int* __restrict__ ex, const int* __restrict__ boff,
                                int* __restrict__ indptr, int* __restrict__ cursor,
                                int n, int total) {
  int i = blockIdx.x * 256 + threadIdx.x;
  if (i < n) {
    int v = ex[i] + boff[i >> 8];
    indptr[i] = v;
    cursor[i] = v;
  }
  if (i == 0) indptr[n] = total;
}

__global__ void k_fill(const int* __restrict__ dst, int* __restrict__ cursor,
                       int* __restrict__ indices, int n) {
  int i = blockIdx.x * blockDim.x + threadIdx.x;
  if (i < n) {
    int pos = atomicAdd(&cursor[dst[i]], 1);
    indices[pos] = i;
  }
}

// ---------------------------------------------------------------- edge scores
__global__ __launch_bounds__(256) void k_edge_score(
    const float* __restrict__ Q, const float* __restrict__ Kb,
    const int* __restrict__ src, const int* __restrict__ dst,
    float* __restrict__ sedge, int ne) {
  int idx = blockIdx.x * blockDim.x + threadIdx.x;
  if (idx >= ne * HH) return;
  int e = idx >> 3;
  int hh = idx & 7;
  const float4* kr = (const float4*)(Kb + (size_t)src[e] * DD + hh * DHH);
  const float4* qr = (const float4*)(Q + (size_t)dst[e] * DD + hh * DHH);
  float dot = 0.f;
#pragma unroll
  for (int d = 0; d < 8; ++d) {
    float4 a = kr[d], b = qr[d];
    dot += a.x * b.x + a.y * b.y + a.z * b.z + a.w * b.w;
  }
  float x = dot * 0.17677669529663687f;  // 1/sqrt(32)
  x = fminf(fmaxf(x, -5.f), 5.f);
  sedge[idx] = expf(x);
}

// ---------------------------------------------------------------- segment softmax + p*V (bf16 out)
__global__ __launch_bounds__(256) void k_aggregate(
    const int* __restrict__ indptr, const int* __restrict__ indices,
    const int* __restrict__ src, const float* __restrict__ sedge,
    const float* __restrict__ V, __hip_bfloat16* __restrict__ attn) {
  int n = blockIdx.x;
  int t = threadIdx.x;
  int hh = t >> 5, lane = t & 31;
  int s0 = indptr[n], s1 = indptr[n + 1];
  float m = 0.f;  // all s > 0 so 0 is a safe identity
  for (int i = s0 + lane; i < s1; i += 32)
    m = fmaxf(m, sedge[(size_t)indices[i] * HH + hh]);
#pragma unroll
  for (int o = 16; o > 0; o >>= 1) m = fmaxf(m, __shfl_xor(m, o, 32));
  float den = 0.f, acc = 0.f;
  for (int i = s0; i < s1; ++i) {
    int e = indices[i];
    float p = expf(sedge[(size_t)e * HH + hh] - m);
    den += p;
    acc += p * V[(size_t)src[e] * DD + hh * DHH + lane];
  }
  attn[(size_t)n * DD + hh * DHH + lane] = __float2bfloat16(acc / (den > 0.f ? den : 1.f));
}

// ---------------------------------------------------------------- residual + LN (f32 + bf16 shadow)
__global__ __launch_bounds__(256) void k_ln(
    float* __restrict__ h, const float* __restrict__ add,
    const float* __restrict__ g, const float* __restrict__ b,
    __hip_bfloat16* __restrict__ hb, int n) {
  int row = blockIdx.x * 4 + (threadIdx.x >> 6);
  int lane = threadIdx.x & 63;
  if (row >= n) return;
  const size_t base = (size_t)row * DD;
  float x[4];
  float s = 0.f;
#pragma unroll
  for (int j = 0; j < 4; ++j) {
    int d = lane + j * 64;
    x[j] = h[base + d] + add[base + d];
    s += x[j];
  }
#pragma unroll
  for (int o = 32; o > 0; o >>= 1) s += __shfl_xor(s, o, 64);
  float mean = s * (1.f / 256.f);
  float vs = 0.f;
#pragma unroll
  for (int j = 0; j < 4; ++j) {
    float d = x[j] - mean;
    vs += d * d;
  }
#pragma unroll
  for (int o = 32; o > 0; o >>= 1) vs += __shfl_xor(vs, o, 64);
  float rs = rsqrtf(vs * (1.f / 256.f) + 1e-5f);
#pragma unroll
  for (int j = 0; j < 4; ++j) {
    int d = lane + j * 64;
    float v = g[d] * ((x[j] - mean) * rs) + b[d];
    h[base + d] = v;
    hb[base + d] = __float2bfloat16(v);
  }
}

// ---------------------------------------------------------------- readout (counts folded in)
__global__ __launch_bounds__(256) void k_gsum(
    const float* __restrict__ h, const int* __restrict__ gid,
    float* __restrict__ gsum, int* __restrict__ gcnt, int n) {
  __shared__ float bins[GG * DD];
  __shared__ int cnt[GG];
  int t = threadIdx.x;
  for (int i = t; i < GG * DD; i += 256) bins[i] = 0.f;
  if (t < GG) cnt[t] = 0;
  __syncthreads();
  for (int nn = blockIdx.x; nn < n; nn += gridDim.x) {
    int g = gid[nn];
    bins[g * DD + t] += h[(size_t)nn * DD + t];
    if (t == 0) cnt[g]++;
  }
  __syncthreads();
  for (int i = t; i < GG * DD; i += 256) atomicAdd(&gsum[i], bins[i]);
  if (t < GG) atomicAdd(&gcnt[t], cnt[t]);
}

__global__ void k_final(const float* __restrict__ gsum, const int* __restrict__ gcnt,
                        float* __restrict__ out) {
  int g = blockIdx.x, t = threadIdx.x;
  int c = gcnt[g];
  out[g * DD + t] = gsum[g * DD + t] / (c > 0 ? (float)c : 1.f);
}

// ---------------------------------------------------------------- launch
extern "C" void kernel_launch(void* const* d_in, const int* in_sizes, int n_in,
                              void* d_out, int out_size, void* d_ws, size_t ws_size,
                              hipStream_t stream) {
  const float* feat = (const float*)d_in[0];
  const float* lap  = (const float*)d_in[1];
  const float* sign = (const float*)d_in[2];
  const int* srcs   = (const int*)d_in[3];
  const int* dsts   = (const int*)d_in[4];
  const int* gids   = (const int*)d_in[5];
  const float* Wh   = (const float*)d_in[6];
  const float* bh   = (const float*)d_in[7];
  const float* Wlp  = (const float*)d_in[8];
  const float* blp  = (const float*)d_in[9];
  const float* Wq   = (const float*)d_in[10];
  const float* Wk   = (const float*)d_in[11];
  const float* Wv   = (const float*)d_in[12];
  const float* Wo   = (const float*)d_in[13];
  const float* bo   = (const float*)d_in[14];
  const float* g1   = (const float*)d_in[15];
  const float* b1   = (const float*)d_in[16];
  const float* W1   = (const float*)d_in[17];
  const float* c1   = (const float*)d_in[18];
  const float* W2   = (const float*)d_in[19];
  const float* c2   = (const float*)d_in[20];
  const float* g2   = (const float*)d_in[21];
  const float* b2   = (const float*)d_in[22];

  char* base = (char*)d_ws;
  size_t off = 0;
  auto take = [&](size_t bytes) -> void* {
    void* p = base + off;
    off += (bytes + 255) & ~(size_t)255;
    return p;
  };
  float* h      = (float*)take((size_t)NN * DD * 4);
  __hip_bfloat16* hb = (__hip_bfloat16*)take((size_t)NN * DD * 2);
  float* Qb     = (float*)take((size_t)NN * DD * 4);
  float* Kb     = (float*)take((size_t)NN * DD * 4);
  float* Vb     = (float*)take((size_t)NN * DD * 4);
  float* sedge  = (float*)take((size_t)EE * HH * 4);
  __hip_bfloat16* t1b = (__hip_bfloat16*)take((size_t)NN * DFF * 2);
  __hip_bfloat16* Wqt = (__hip_bfloat16*)take((size_t)LLAYERS * DD * DD * 2);
  __hip_bfloat16* Wkt = (__hip_bfloat16*)take((size_t)LLAYERS * DD * DD * 2);
  __hip_bfloat16* Wvt = (__hip_bfloat16*)take((size_t)LLAYERS * DD * DD * 2);
  __hip_bfloat16* Wot = (__hip_bfloat16*)take((size_t)LLAYERS * DD * DD * 2);
  __hip_bfloat16* W1t = (__hip_bfloat16*)take((size_t)LLAYERS * DD * DFF * 2);
  __hip_bfloat16* W2t = (__hip_bfloat16*)take((size_t)LLAYERS * DFF * DD * 2);
  int* deg     = (int*)take((size_t)NN * 4);
  int* ex      = (int*)take((size_t)NN * 4);
  int* bsum    = (int*)take(256 * 4);
  int* boff    = (int*)take(256 * 4);
  int* indptr  = (int*)take((size_t)(NN + 1) * 4);
  int* cursor  = (int*)take((size_t)NN * 4);
  int* indices = (int*)take((size_t)EE * 4);
  float* gsum  = (float*)take((size_t)GG * DD * 4);
  int* gcnt    = (int*)take((size_t)GG * 4);
  __hip_bfloat16* attnb = (__hip_bfloat16*)Qb;  // Q dead after edge scores
  float* tmp = Kb;                              // K dead after edge scores

  const int NB = (NN + 255) / 256;

  // weight convert+transpose (bf16, [N][K])
  k_wt<<<dim3(DD / 32, DD / 32, LLAYERS), 256, 0, stream>>>(Wq, Wqt, DD, DD);
  k_wt<<<dim3(DD / 32, DD / 32, LLAYERS), 256, 0, stream>>>(Wk, Wkt, DD, DD);
  k_wt<<<dim3(DD / 32, DD / 32, LLAYERS), 256, 0, stream>>>(Wv, Wvt, DD, DD);
  k_wt<<<dim3(DD / 32, DD / 32, LLAYERS), 256, 0, stream>>>(Wo, Wot, DD, DD);
  k_wt<<<dim3(DFF / 32, DD / 32, LLAYERS), 256, 0, stream>>>(W1, W1t, DD, DFF);
  k_wt<<<dim3(DD / 32, DFF / 32, LLAYERS), 256, 0, stream>>>(W2, W2t, DFF, DD);

  // CSR by dst
  hipMemsetAsync(deg, 0, (size_t)NN * 4, stream);
  k_hist<<<(EE + 255) / 256, 256, 0, stream>>>(dsts, deg, EE);
  k_scan_block<<<NB, 256, 0, stream>>>(deg, ex, bsum, NN);
  k_scan_top<<<1, 256, 0, stream>>>(bsum, boff, NB);
  k_finish_indptr<<<NB, 256, 0, stream>>>(ex, boff, indptr, cursor, NN, EE);
  k_fill<<<(EE + 255) / 256, 256, 0, stream>>>(dsts, cursor, indices, EE);

  // embedding
  k_embed<<<NN, 256, 0, stream>>>(feat, lap, sign, Wh, bh, Wlp, blp, h, hb);

  const int MB = (NN + 127) / 128;  // 157
  dim3 gQKV(MB, DD / 128, 3);
  dim3 gD(MB, DD / 128, 1);
  dim3 gF(MB, DFF / 128, 1);

  for (int l = 0; l < LLAYERS; ++l) {
    const __hip_bfloat16* Wqt_l = Wqt + (size_t)l * DD * DD;
    const __hip_bfloat16* Wkt_l = Wkt + (size_t)l * DD * DD;
    const __hip_bfloat16* Wvt_l = Wvt + (size_t)l * DD * DD;
    const __hip_bfloat16* Wot_l = Wot + (size_t)l * DD * DD;
    const __hip_bfloat16* W1t_l = W1t + (size_t)l * DD * DFF;
    const __hip_bfloat16* W2t_l = W2t + (size_t)l * DFF * DD;
    const float* bo_l = bo + (size_t)l * DD;
    const float* g1_l = g1 + (size_t)l * DD;
    const float* b1_l = b1 + (size_t)l * DD;
    const float* c1_l = c1 + (size_t)l * DFF;
    const float* c2_l = c2 + (size_t)l * DD;
    const float* g2_l = g2 + (size_t)l * DD;
    const float* b2_l = b2 + (size_t)l * DD;

    gemm_mfma<false, false, false><<<gQKV, 256, 0, stream>>>(
        hb, Wqt_l, Wkt_l, Wvt_l, nullptr, Qb, Kb, Vb, NN, DD, DD);

    k_edge_score<<<((size_t)EE * HH + 255) / 256, 256, 0, stream>>>(Qb, Kb, srcs, dsts, sedge, EE);
    k_aggregate<<<NN, 256, 0, stream>>>(indptr, indices, srcs, sedge, Vb, attnb);

    gemm_mfma<true, false, false><<<gD, 256, 0, stream>>>(
        attnb, Wot_l, Wot_l, Wot_l, bo_l, tmp, tmp, tmp, NN, DD, DD);
    k_ln<<<NN / 4, 256, 0, stream>>>(h, tmp, g1_l, b1_l, hb, NN);

    gemm_mfma<true, true, true><<<gF, 256, 0, stream>>>(
        hb, W1t_l, W1t_l, W1t_l, c1_l, t1b, t1b, t1b, NN, DFF, DD);
    gemm_mfma<true, false, false><<<gD, 256, 0, stream>>>(
        t1b, W2t_l, W2t_l, W2t_l, c2_l, tmp, tmp, tmp, NN, DD, DFF);
    k_ln<<<NN / 4, 256, 0, stream>>>(h, tmp, g2_l, b2_l, hb, NN);
  }

  hipMemsetAsync(gsum, 0, (size_t)GG * DD * 4, stream);
  hipMemsetAsync(gcnt, 0, (size_t)GG * 4, stream);
  k_gsum<<<64, 256, 0, stream>>>(h, gids, gsum, gcnt, NN);
  k_final<<<GG, 256, 0, stream>>>(gsum, gcnt, (float*)d_out);
}

// Round 3
// 694.492 us; speedup vs baseline: 2.2153x; 1.3071x over previous
//
#include <hip/hip_runtime.h>
#include <hip/hip_bf16.h>

#define NN   20000
#define EE   320000
#define GG   16
#define DD   256
#define HH   8
#define DHH  32
#define LLAYERS 2
#define DFF  512
#define DIN  32
#define DLAP 16

typedef __attribute__((ext_vector_type(8))) short bf16x8;
typedef __attribute__((ext_vector_type(4))) float f32x4;

__device__ __forceinline__ void gld_lds16(const void* g, void* l) {
  __builtin_amdgcn_global_load_lds((const __attribute__((address_space(1))) uint32_t*)g,
                                   (__attribute__((address_space(3))) uint32_t*)l, 16, 0, 0);
}

__device__ __forceinline__ float b2f(short s) {
  union { int i; float f; } u;
  u.i = ((int)(unsigned short)s) << 16;
  return u.f;
}

// ---------------------------------------------------------------- embed (f32 + bf16 shadow)
__global__ __launch_bounds__(256) void k_embed(
    const float* __restrict__ feat, const float* __restrict__ lap,
    const float* __restrict__ sign, const float* __restrict__ Wh,
    const float* __restrict__ bh, const float* __restrict__ Wlp,
    const float* __restrict__ blp, float* __restrict__ h,
    __hip_bfloat16* __restrict__ hb) {
  int n = blockIdx.x;
  int d = threadIdx.x;
  float acc = bh[d] + blp[d];
  const float* frow = feat + (size_t)n * DIN;
  const float* lrow = lap + (size_t)n * DLAP;
#pragma unroll
  for (int k = 0; k < DIN; ++k) acc += frow[k] * Wh[k * DD + d];
#pragma unroll
  for (int k = 0; k < DLAP; ++k) acc += (lrow[k] * sign[k]) * Wlp[k * DD + d];
  h[(size_t)n * DD + d] = acc;
  hb[(size_t)n * DD + d] = __float2bfloat16(acc);
}

// ---------------------------------------------------------------- weight transpose+convert
__global__ __launch_bounds__(256) void k_wt(
    const float* __restrict__ in, __hip_bfloat16* __restrict__ out, int K, int N) {
  __shared__ float tile[32][33];
  const float* inl = in + (size_t)blockIdx.z * K * N;
  __hip_bfloat16* outl = out + (size_t)blockIdx.z * N * K;
  int bx = blockIdx.x;
  int by = blockIdx.y;
  int tx = threadIdx.x & 31, ty = threadIdx.x >> 5;
#pragma unroll
  for (int i = 0; i < 32; i += 8)
    tile[ty + i][tx] = inl[(size_t)(by * 32 + ty + i) * N + bx * 32 + tx];
  __syncthreads();
#pragma unroll
  for (int i = 0; i < 32; i += 8)
    outl[(size_t)(bx * 32 + ty + i) * K + by * 32 + tx] = __float2bfloat16(tile[tx][ty + i]);
}

// ---------------------------------------------------------------- MFMA bf16 GEMM (128x128, BK=32)
template <bool BIAS, bool RELU, bool OUTBF16>
__global__ __launch_bounds__(256) void gemm_mfma(
    const __hip_bfloat16* __restrict__ A,
    const __hip_bfloat16* __restrict__ Bt0, const __hip_bfloat16* __restrict__ Bt1,
    const __hip_bfloat16* __restrict__ Bt2,
    const float* __restrict__ bias,
    void* __restrict__ C0, void* __restrict__ C1, void* __restrict__ C2,
    int M, int Ncols, int K) {
  const __hip_bfloat16* Bt = (blockIdx.z == 0) ? Bt0 : (blockIdx.z == 1) ? Bt1 : Bt2;
  void* Cout = (blockIdx.z == 0) ? C0 : (blockIdx.z == 1) ? C1 : C2;

  __shared__ short lA[2][4][128][8];
  __shared__ short lB[2][4][128][8];

  const int t = threadIdx.x;
  const int lane = t & 63, w = t >> 6;
  const int bm = blockIdx.x * 128, bn = blockIdx.y * 128;
  const int wr = w >> 1, wc = w & 1;
  const int fr = lane & 15, fg = lane >> 4;

  f32x4 acc[4][4] = {};

  auto stage = [&](int buf, int kt) {
    const int k0 = kt * 32;
#pragma unroll
    for (int it = 0; it < 2; ++it) {
      const int cbase = it * 256 + w * 64;
      const int c = cbase + lane;
      const int g = c >> 7, r = c & 127;
      int arow = bm + r;
      if (arow >= M) arow = M - 1;
      gld_lds16(A + (size_t)arow * K + k0 + g * 8,
                (short*)lA + ((size_t)buf * 4 * 128 + cbase) * 8);
      gld_lds16(Bt + (size_t)(bn + r) * K + k0 + g * 8,
                (short*)lB + ((size_t)buf * 4 * 128 + cbase) * 8);
    }
  };

  const int nt = K >> 5;
  stage(0, 0);
  for (int kt = 0; kt < nt; ++kt) {
    const int buf = kt & 1;
    __syncthreads();
    if (kt + 1 < nt) stage(buf ^ 1, kt + 1);
    bf16x8 af[4], bfr[4];
#pragma unroll
    for (int i = 0; i < 4; ++i)
      af[i] = *(const bf16x8*)&lA[buf][fg][wr * 64 + i * 16 + fr][0];
#pragma unroll
    for (int j = 0; j < 4; ++j)
      bfr[j] = *(const bf16x8*)&lB[buf][fg][wc * 64 + j * 16 + fr][0];
#pragma unroll
    for (int i = 0; i < 4; ++i)
#pragma unroll
      for (int j = 0; j < 4; ++j)
        acc[i][j] = __builtin_amdgcn_mfma_f32_16x16x32_bf16(af[i], bfr[j], acc[i][j], 0, 0, 0);
  }

#pragma unroll
  for (int i = 0; i < 4; ++i) {
    const int row0 = bm + wr * 64 + i * 16 + fg * 4;
#pragma unroll
    for (int j = 0; j < 4; ++j) {
      const int col = bn + wc * 64 + j * 16 + fr;
      float bv = BIAS ? bias[col] : 0.f;
#pragma unroll
      for (int r = 0; r < 4; ++r) {
        const int row = row0 + r;
        if (row >= M) continue;
        float v = acc[i][j][r] + bv;
        if (RELU) v = fmaxf(v, 0.f);
        if (OUTBF16)
          ((__hip_bfloat16*)Cout)[(size_t)row * Ncols + col] = __float2bfloat16(v);
        else
          ((float*)Cout)[(size_t)row * Ncols + col] = v;
      }
    }
  }
}

// ---------------------------------------------------------------- CSR build
__global__ void k_hist(const int* __restrict__ dst, int* __restrict__ deg, int n) {
  int i = blockIdx.x * blockDim.x + threadIdx.x;
  if (i < n) atomicAdd(&deg[dst[i]], 1);
}

__global__ __launch_bounds__(256) void k_scan_block(
    const int* __restrict__ in, int* __restrict__ ex, int* __restrict__ bsum, int n) {
  __shared__ int sm[256];
  int t = threadIdx.x;
  int i = blockIdx.x * 256 + t;
  int v = (i < n) ? in[i] : 0;
  sm[t] = v;
  __syncthreads();
  for (int o = 1; o < 256; o <<= 1) {
    int x = (t >= o) ? sm[t - o] : 0;
    __syncthreads();
    sm[t] += x;
    __syncthreads();
  }
  if (i < n) ex[i] = sm[t] - v;
  if (t == 255) bsum[blockIdx.x] = sm[255];
}

__global__ __launch_bounds__(256) void k_scan_top(
    const int* __restrict__ bsum, int* __restrict__ boff, int nb) {
  __shared__ int sm[256];
  int t = threadIdx.x;
  int v = (t < nb) ? bsum[t] : 0;
  sm[t] = v;
  __syncthreads();
  for (int o = 1; o < 256; o <<= 1) {
    int x = (t >= o) ? sm[t - o] : 0;
    __syncthreads();
    sm[t] += x;
    __syncthreads();
  }
  if (t < nb) boff[t] = sm[t] - v;
}

__global__ void k_finish_indptr(const int* __restrict__ ex, const int* __restrict__ boff,
                                int* __restrict__ indptr, int* __restrict__ cursor,
                                int n, int total) {
  int i = blockIdx.x * 256 + threadIdx.x;
  if (i < n) {
    int v = ex[i] + boff[i >> 8];
    indptr[i] = v;
    cursor[i] = v;
  }
  if (i == 0) indptr[n] = total;
}

// fill CSR: csr_src[pos] = src[e]; epos[e] = pos
__global__ void k_fill(const int* __restrict__ dst, const int* __restrict__ src,
                       int* __restrict__ cursor, int* __restrict__ csr_src,
                       int* __restrict__ epos, int n) {
  int i = blockIdx.x * blockDim.x + threadIdx.x;
  if (i < n) {
    int pos = atomicAdd(&cursor[dst[i]], 1);
    csr_src[pos] = src[i];
    epos[i] = pos;
  }
}

// ---------------------------------------------------------------- edge scores (bf16 in, CSR-ordered out, fused segment-max)
__global__ __launch_bounds__(256) void k_edge_score(
    const __hip_bfloat16* __restrict__ Q, const __hip_bfloat16* __restrict__ Kb,
    const int* __restrict__ src, const int* __restrict__ dst,
    const int* __restrict__ epos,
    float* __restrict__ sedge, int* __restrict__ mbuf, int ne) {
  int idx = blockIdx.x * blockDim.x + threadIdx.x;
  if (idx >= ne * HH) return;
  int e = idx >> 3;
  int hh = idx & 7;
  const bf16x8* kr = (const bf16x8*)(Kb + (size_t)src[e] * DD + hh * DHH);
  const bf16x8* qr = (const bf16x8*)(Q + (size_t)dst[e] * DD + hh * DHH);
  float dot = 0.f;
#pragma unroll
  for (int c = 0; c < 4; ++c) {
    bf16x8 a = kr[c], b = qr[c];
#pragma unroll
    for (int u = 0; u < 8; ++u) dot += b2f(a[u]) * b2f(b[u]);
  }
  float x = dot * 0.17677669529663687f;  // 1/sqrt(32)
  x = fminf(fmaxf(x, -5.f), 5.f);
  float s = expf(x);
  sedge[(size_t)epos[e] * HH + hh] = s;
  atomicMax(&mbuf[dst[e] * HH + hh], __float_as_int(s));  // s>0: int-bit order == float order
}

// ---------------------------------------------------------------- single-pass segment softmax + p*V
__global__ __launch_bounds__(256) void k_aggregate(
    const int* __restrict__ indptr, const int* __restrict__ csr_src,
    const float* __restrict__ sedge, const int* __restrict__ mbuf,
    const __hip_bfloat16* __restrict__ V, __hip_bfloat16* __restrict__ attn) {
  int n = blockIdx.x;
  int t = threadIdx.x;
  int hh = t >> 5, lane = t & 31;
  int s0 = indptr[n], s1 = indptr[n + 1];
  float m = __int_as_float(mbuf[n * HH + hh]);
  float den = 0.f, acc = 0.f;
  for (int basei = s0; basei < s1; basei += 32) {
    int j = basei + lane;
    float p = 0.f;
    int srcv = 0;
    if (j < s1) {
      p = expf(sedge[(size_t)j * HH + hh] - m);
      srcv = csr_src[j];
    }
    den += p;
    int cnt = min(32, s1 - basei);
    for (int k = 0; k < cnt; ++k) {
      float pk = __shfl(p, k, 32);
      int srow = __shfl(srcv, k, 32);
      acc += pk * b2f(((const short*)V)[(size_t)srow * DD + hh * DHH + lane]);
    }
  }
#pragma unroll
  for (int o = 16; o > 0; o >>= 1) den += __shfl_xor(den, o, 32);
  attn[(size_t)n * DD + hh * DHH + lane] = __float2bfloat16(acc / (den > 0.f ? den : 1.f));
}

// ---------------------------------------------------------------- residual + LN (f32 + bf16 shadow)
__global__ __launch_bounds__(256) void k_ln(
    float* __restrict__ h, const float* __restrict__ add,
    const float* __restrict__ g, const float* __restrict__ b,
    __hip_bfloat16* __restrict__ hb, int n) {
  int row = blockIdx.x * 4 + (threadIdx.x >> 6);
  int lane = threadIdx.x & 63;
  if (row >= n) return;
  const size_t base = (size_t)row * DD;
  float x[4];
  float s = 0.f;
#pragma unroll
  for (int j = 0; j < 4; ++j) {
    int d = lane + j * 64;
    x[j] = h[base + d] + add[base + d];
    s += x[j];
  }
#pragma unroll
  for (int o = 32; o > 0; o >>= 1) s += __shfl_xor(s, o, 64);
  float mean = s * (1.f / 256.f);
  float vs = 0.f;
#pragma unroll
  for (int j = 0; j < 4; ++j) {
    float d = x[j] - mean;
    vs += d * d;
  }
#pragma unroll
  for (int o = 32; o > 0; o >>= 1) vs += __shfl_xor(vs, o, 64);
  float rs = rsqrtf(vs * (1.f / 256.f) + 1e-5f);
#pragma unroll
  for (int j = 0; j < 4; ++j) {
    int d = lane + j * 64;
    float v = g[d] * ((x[j] - mean) * rs) + b[d];
    h[base + d] = v;
    hb[base + d] = __float2bfloat16(v);
  }
}

// ---------------------------------------------------------------- readout
__global__ __launch_bounds__(256) void k_gsum(
    const float* __restrict__ h, const int* __restrict__ gid,
    float* __restrict__ gsum, int* __restrict__ gcnt, int n) {
  __shared__ float bins[GG * DD];
  __shared__ int cnt[GG];
  int t = threadIdx.x;
  for (int i = t; i < GG * DD; i += 256) bins[i] = 0.f;
  if (t < GG) cnt[t] = 0;
  __syncthreads();
  for (int nn = blockIdx.x; nn < n; nn += gridDim.x) {
    int g = gid[nn];
    bins[g * DD + t] += h[(size_t)nn * DD + t];
    if (t == 0) cnt[g]++;
  }
  __syncthreads();
  for (int i = t; i < GG * DD; i += 256) atomicAdd(&gsum[i], bins[i]);
  if (t < GG) atomicAdd(&gcnt[t], cnt[t]);
}

__global__ void k_final(const float* __restrict__ gsum, const int* __restrict__ gcnt,
                        float* __restrict__ out) {
  int g = blockIdx.x, t = threadIdx.x;
  int c = gcnt[g];
  out[g * DD + t] = gsum[g * DD + t] / (c > 0 ? (float)c : 1.f);
}

// ---------------------------------------------------------------- launch
extern "C" void kernel_launch(void* const* d_in, const int* in_sizes, int n_in,
                              void* d_out, int out_size, void* d_ws, size_t ws_size,
                              hipStream_t stream) {
  const float* feat = (const float*)d_in[0];
  const float* lap  = (const float*)d_in[1];
  const float* sign = (const float*)d_in[2];
  const int* srcs   = (const int*)d_in[3];
  const int* dsts   = (const int*)d_in[4];
  const int* gids   = (const int*)d_in[5];
  const float* Wh   = (const float*)d_in[6];
  const float* bh   = (const float*)d_in[7];
  const float* Wlp  = (const float*)d_in[8];
  const float* blp  = (const float*)d_in[9];
  const float* Wq   = (const float*)d_in[10];
  const float* Wk   = (const float*)d_in[11];
  const float* Wv   = (const float*)d_in[12];
  const float* Wo   = (const float*)d_in[13];
  const float* bo   = (const float*)d_in[14];
  const float* g1   = (const float*)d_in[15];
  const float* b1   = (const float*)d_in[16];
  const float* W1   = (const float*)d_in[17];
  const float* c1   = (const float*)d_in[18];
  const float* W2   = (const float*)d_in[19];
  const float* c2   = (const float*)d_in[20];
  const float* g2   = (const float*)d_in[21];
  const float* b2   = (const float*)d_in[22];

  char* base = (char*)d_ws;
  size_t off = 0;
  auto take = [&](size_t bytes) -> void* {
    void* p = base + off;
    off += (bytes + 255) & ~(size_t)255;
    return p;
  };
  float* h      = (float*)take((size_t)NN * DD * 4);
  __hip_bfloat16* hb = (__hip_bfloat16*)take((size_t)NN * DD * 2);
  __hip_bfloat16* Qb = (__hip_bfloat16*)take((size_t)NN * DD * 2);
  __hip_bfloat16* Kb = (__hip_bfloat16*)take((size_t)NN * DD * 2);
  __hip_bfloat16* Vb = (__hip_bfloat16*)take((size_t)NN * DD * 2);
  float* tmp    = (float*)take((size_t)NN * DD * 4);
  float* sedge  = (float*)take((size_t)EE * HH * 4);
  __hip_bfloat16* t1b = (__hip_bfloat16*)take((size_t)NN * DFF * 2);
  __hip_bfloat16* Wqt = (__hip_bfloat16*)take((size_t)LLAYERS * DD * DD * 2);
  __hip_bfloat16* Wkt = (__hip_bfloat16*)take((size_t)LLAYERS * DD * DD * 2);
  __hip_bfloat16* Wvt = (__hip_bfloat16*)take((size_t)LLAYERS * DD * DD * 2);
  __hip_bfloat16* Wot = (__hip_bfloat16*)take((size_t)LLAYERS * DD * DD * 2);
  __hip_bfloat16* W1t = (__hip_bfloat16*)take((size_t)LLAYERS * DD * DFF * 2);
  __hip_bfloat16* W2t = (__hip_bfloat16*)take((size_t)LLAYERS * DFF * DD * 2);
  int* deg     = (int*)take((size_t)NN * 4);
  int* ex      = (int*)take((size_t)NN * 4);
  int* bsum    = (int*)take(256 * 4);
  int* boff    = (int*)take(256 * 4);
  int* indptr  = (int*)take((size_t)(NN + 1) * 4);
  int* cursor  = (int*)take((size_t)NN * 4);
  int* csr_src = (int*)take((size_t)EE * 4);
  int* epos    = (int*)take((size_t)EE * 4);
  int* mbuf    = (int*)take((size_t)NN * HH * 4);
  float* gsum  = (float*)take((size_t)GG * DD * 4);
  int* gcnt    = (int*)take((size_t)GG * 4);
  __hip_bfloat16* attnb = Qb;  // Q dead after edge scores

  const int NB = (NN + 255) / 256;

  // weight convert+transpose
  k_wt<<<dim3(DD / 32, DD / 32, LLAYERS), 256, 0, stream>>>(Wq, Wqt, DD, DD);
  k_wt<<<dim3(DD / 32, DD / 32, LLAYERS), 256, 0, stream>>>(Wk, Wkt, DD, DD);
  k_wt<<<dim3(DD / 32, DD / 32, LLAYERS), 256, 0, stream>>>(Wv, Wvt, DD, DD);
  k_wt<<<dim3(DD / 32, DD / 32, LLAYERS), 256, 0, stream>>>(Wo, Wot, DD, DD);
  k_wt<<<dim3(DFF / 32, DD / 32, LLAYERS), 256, 0, stream>>>(W1, W1t, DD, DFF);
  k_wt<<<dim3(DD / 32, DFF / 32, LLAYERS), 256, 0, stream>>>(W2, W2t, DFF, DD);

  // CSR by dst
  hipMemsetAsync(deg, 0, (size_t)NN * 4, stream);
  k_hist<<<(EE + 255) / 256, 256, 0, stream>>>(dsts, deg, EE);
  k_scan_block<<<NB, 256, 0, stream>>>(deg, ex, bsum, NN);
  k_scan_top<<<1, 256, 0, stream>>>(bsum, boff, NB);
  k_finish_indptr<<<NB, 256, 0, stream>>>(ex, boff, indptr, cursor, NN, EE);
  k_fill<<<(EE + 255) / 256, 256, 0, stream>>>(dsts, srcs, cursor, csr_src, epos, EE);

  // embedding
  k_embed<<<NN, 256, 0, stream>>>(feat, lap, sign, Wh, bh, Wlp, blp, h, hb);

  const int MB = (NN + 127) / 128;  // 157
  dim3 gQKV(MB, DD / 128, 3);
  dim3 gD(MB, DD / 128, 1);
  dim3 gF(MB, DFF / 128, 1);

  for (int l = 0; l < LLAYERS; ++l) {
    const __hip_bfloat16* Wqt_l = Wqt + (size_t)l * DD * DD;
    const __hip_bfloat16* Wkt_l = Wkt + (size_t)l * DD * DD;
    const __hip_bfloat16* Wvt_l = Wvt + (size_t)l * DD * DD;
    const __hip_bfloat16* Wot_l = Wot + (size_t)l * DD * DD;
    const __hip_bfloat16* W1t_l = W1t + (size_t)l * DD * DFF;
    const __hip_bfloat16* W2t_l = W2t + (size_t)l * DFF * DD;
    const float* bo_l = bo + (size_t)l * DD;
    const float* g1_l = g1 + (size_t)l * DD;
    const float* b1_l = b1 + (size_t)l * DD;
    const float* c1_l = c1 + (size_t)l * DFF;
    const float* c2_l = c2 + (size_t)l * DD;
    const float* g2_l = g2 + (size_t)l * DD;
    const float* b2_l = b2 + (size_t)l * DD;

    gemm_mfma<false, false, true><<<gQKV, 256, 0, stream>>>(
        hb, Wqt_l, Wkt_l, Wvt_l, nullptr, Qb, Kb, Vb, NN, DD, DD);

    hipMemsetAsync(mbuf, 0, (size_t)NN * HH * 4, stream);
    k_edge_score<<<((size_t)EE * HH + 255) / 256, 256, 0, stream>>>(
        Qb, Kb, srcs, dsts, epos, sedge, mbuf, EE);
    k_aggregate<<<NN, 256, 0, stream>>>(indptr, csr_src, sedge, mbuf, Vb, attnb);

    gemm_mfma<true, false, false><<<gD, 256, 0, stream>>>(
        attnb, Wot_l, Wot_l, Wot_l, bo_l, tmp, tmp, tmp, NN, DD, DD);
    k_ln<<<NN / 4, 256, 0, stream>>>(h, tmp, g1_l, b1_l, hb, NN);

    gemm_mfma<true, true, true><<<gF, 256, 0, stream>>>(
        hb, W1t_l, W1t_l, W1t_l, c1_l, t1b, t1b, t1b, NN, DFF, DD);
    gemm_mfma<true, false, false><<<gD, 256, 0, stream>>>(
        t1b, W2t_l, W2t_l, W2t_l, c2_l, tmp, tmp, tmp, NN, DD, DFF);
    k_ln<<<NN / 4, 256, 0, stream>>>(h, tmp, g2_l, b2_l, hb, NN);
  }

  hipMemsetAsync(gsum, 0, (size_t)GG * DD * 4, stream);
  hipMemsetAsync(gcnt, 0, (size_t)GG * 4, stream);
  k_gsum<<<64, 256, 0, stream>>>(h, gids, gsum, gcnt, NN);
  k_final<<<GG, 256, 0, stream>>>(gsum, gcnt, (float*)d_out);
}

// Round 4
// 610.553 us; speedup vs baseline: 2.5198x; 1.1375x over previous
//
#include <hip/hip_runtime.h>
#include <hip/hip_bf16.h>

#define NN   20000
#define EE   320000
#define GG   16
#define DD   256
#define HH   8
#define DHH  32
#define LLAYERS 2
#define DFF  512
#define DIN  32
#define DLAP 16
#define RSPLITS 16

typedef __attribute__((ext_vector_type(8))) short bf16x8;
typedef __attribute__((ext_vector_type(4))) float f32x4;

__device__ __forceinline__ void gld_lds16(const void* g, void* l) {
  __builtin_amdgcn_global_load_lds((const __attribute__((address_space(1))) uint32_t*)g,
                                   (__attribute__((address_space(3))) uint32_t*)l, 16, 0, 0);
}

__device__ __forceinline__ float b2f(short s) {
  union { int i; float f; } u;
  u.i = ((int)(unsigned short)s) << 16;
  return u.f;
}

// ---------------------------------------------------------------- embed (f32 + bf16 shadow)
__global__ __launch_bounds__(256) void k_embed(
    const float* __restrict__ feat, const float* __restrict__ lap,
    const float* __restrict__ sign, const float* __restrict__ Wh,
    const float* __restrict__ bh, const float* __restrict__ Wlp,
    const float* __restrict__ blp, float* __restrict__ h,
    __hip_bfloat16* __restrict__ hb) {
  int n = blockIdx.x;
  int d = threadIdx.x;
  float acc = bh[d] + blp[d];
  const float* frow = feat + (size_t)n * DIN;
  const float* lrow = lap + (size_t)n * DLAP;
#pragma unroll
  for (int k = 0; k < DIN; ++k) acc += frow[k] * Wh[k * DD + d];
#pragma unroll
  for (int k = 0; k < DLAP; ++k) acc += (lrow[k] * sign[k]) * Wlp[k * DD + d];
  h[(size_t)n * DD + d] = acc;
  hb[(size_t)n * DD + d] = __float2bfloat16(acc);
}

// ---------------------------------------------------------------- weight transpose+convert
__global__ __launch_bounds__(256) void k_wt(
    const float* __restrict__ in, __hip_bfloat16* __restrict__ out, int K, int N) {
  __shared__ float tile[32][33];
  const float* inl = in + (size_t)blockIdx.z * K * N;
  __hip_bfloat16* outl = out + (size_t)blockIdx.z * N * K;
  int bx = blockIdx.x;
  int by = blockIdx.y;
  int tx = threadIdx.x & 31, ty = threadIdx.x >> 5;
#pragma unroll
  for (int i = 0; i < 32; i += 8)
    tile[ty + i][tx] = inl[(size_t)(by * 32 + ty + i) * N + bx * 32 + tx];
  __syncthreads();
#pragma unroll
  for (int i = 0; i < 32; i += 8)
    outl[(size_t)(bx * 32 + ty + i) * K + by * 32 + tx] = __float2bfloat16(tile[tx][ty + i]);
}

// ---------------------------------------------------------------- MFMA bf16 GEMM (128x128, BK=32)
template <bool BIAS, bool RELU, bool OUTBF16>
__global__ __launch_bounds__(256) void gemm_mfma(
    const __hip_bfloat16* __restrict__ A,
    const __hip_bfloat16* __restrict__ Bt0, const __hip_bfloat16* __restrict__ Bt1,
    const __hip_bfloat16* __restrict__ Bt2,
    const float* __restrict__ bias,
    void* __restrict__ C0, void* __restrict__ C1, void* __restrict__ C2,
    int M, int Ncols, int K) {
  const __hip_bfloat16* Bt = (blockIdx.z == 0) ? Bt0 : (blockIdx.z == 1) ? Bt1 : Bt2;
  void* Cout = (blockIdx.z == 0) ? C0 : (blockIdx.z == 1) ? C1 : C2;

  __shared__ short lA[2][4][128][8];
  __shared__ short lB[2][4][128][8];

  const int t = threadIdx.x;
  const int lane = t & 63, w = t >> 6;
  const int bm = blockIdx.x * 128, bn = blockIdx.y * 128;
  const int wr = w >> 1, wc = w & 1;
  const int fr = lane & 15, fg = lane >> 4;

  f32x4 acc[4][4] = {};

  auto stage = [&](int buf, int kt) {
    const int k0 = kt * 32;
#pragma unroll
    for (int it = 0; it < 2; ++it) {
      const int cbase = it * 256 + w * 64;
      const int c = cbase + lane;
      const int g = c >> 7, r = c & 127;
      int arow = bm + r;
      if (arow >= M) arow = M - 1;
      gld_lds16(A + (size_t)arow * K + k0 + g * 8,
                (short*)lA + ((size_t)buf * 4 * 128 + cbase) * 8);
      gld_lds16(Bt + (size_t)(bn + r) * K + k0 + g * 8,
                (short*)lB + ((size_t)buf * 4 * 128 + cbase) * 8);
    }
  };

  const int nt = K >> 5;
  stage(0, 0);
  for (int kt = 0; kt < nt; ++kt) {
    const int buf = kt & 1;
    __syncthreads();
    if (kt + 1 < nt) stage(buf ^ 1, kt + 1);
    bf16x8 af[4], bfr[4];
#pragma unroll
    for (int i = 0; i < 4; ++i)
      af[i] = *(const bf16x8*)&lA[buf][fg][wr * 64 + i * 16 + fr][0];
#pragma unroll
    for (int j = 0; j < 4; ++j)
      bfr[j] = *(const bf16x8*)&lB[buf][fg][wc * 64 + j * 16 + fr][0];
#pragma unroll
    for (int i = 0; i < 4; ++i)
#pragma unroll
      for (int j = 0; j < 4; ++j)
        acc[i][j] = __builtin_amdgcn_mfma_f32_16x16x32_bf16(af[i], bfr[j], acc[i][j], 0, 0, 0);
  }

#pragma unroll
  for (int i = 0; i < 4; ++i) {
    const int row0 = bm + wr * 64 + i * 16 + fg * 4;
#pragma unroll
    for (int j = 0; j < 4; ++j) {
      const int col = bn + wc * 64 + j * 16 + fr;
      float bv = BIAS ? bias[col] : 0.f;
#pragma unroll
      for (int r = 0; r < 4; ++r) {
        const int row = row0 + r;
        if (row >= M) continue;
        float v = acc[i][j][r] + bv;
        if (RELU) v = fmaxf(v, 0.f);
        if (OUTBF16)
          ((__hip_bfloat16*)Cout)[(size_t)row * Ncols + col] = __float2bfloat16(v);
        else
          ((float*)Cout)[(size_t)row * Ncols + col] = v;
      }
    }
  }
}

// ---------------------------------------------------------------- CSR build
__global__ void k_hist(const int* __restrict__ dst, int* __restrict__ deg, int n) {
  int i = blockIdx.x * blockDim.x + threadIdx.x;
  if (i < n) atomicAdd(&deg[dst[i]], 1);
}

__global__ __launch_bounds__(256) void k_scan_block(
    const int* __restrict__ in, int* __restrict__ ex, int* __restrict__ bsum, int n) {
  __shared__ int sm[256];
  int t = threadIdx.x;
  int i = blockIdx.x * 256 + t;
  int v = (i < n) ? in[i] : 0;
  sm[t] = v;
  __syncthreads();
  for (int o = 1; o < 256; o <<= 1) {
    int x = (t >= o) ? sm[t - o] : 0;
    __syncthreads();
    sm[t] += x;
    __syncthreads();
  }
  if (i < n) ex[i] = sm[t] - v;
  if (t == 255) bsum[blockIdx.x] = sm[255];
}

__global__ __launch_bounds__(256) void k_scan_top(
    const int* __restrict__ bsum, int* __restrict__ boff, int nb) {
  __shared__ int sm[256];
  int t = threadIdx.x;
  int v = (t < nb) ? bsum[t] : 0;
  sm[t] = v;
  __syncthreads();
  for (int o = 1; o < 256; o <<= 1) {
    int x = (t >= o) ? sm[t - o] : 0;
    __syncthreads();
    sm[t] += x;
    __syncthreads();
  }
  if (t < nb) boff[t] = sm[t] - v;
}

__global__ void k_finish_indptr(const int* __restrict__ ex, const int* __restrict__ boff,
                                int* __restrict__ indptr, int* __restrict__ cursor,
                                int n, int total) {
  int i = blockIdx.x * 256 + threadIdx.x;
  if (i < n) {
    int v = ex[i] + boff[i >> 8];
    indptr[i] = v;
    cursor[i] = v;
  }
  if (i == 0) indptr[n] = total;
}

__global__ void k_fill(const int* __restrict__ dst, const int* __restrict__ src,
                       int* __restrict__ cursor, int* __restrict__ csr_src,
                       int* __restrict__ epos, int n) {
  int i = blockIdx.x * blockDim.x + threadIdx.x;
  if (i < n) {
    int pos = atomicAdd(&cursor[dst[i]], 1);
    csr_src[pos] = src[i];
    epos[i] = pos;
  }
}

// graph boundaries from sorted gids: gb[g] = first node of graph g, gb[GG] = n
__global__ void k_bounds(const int* __restrict__ gid, int* __restrict__ gb, int n) {
  int i = blockIdx.x * blockDim.x + threadIdx.x;
  if (i >= n) return;
  int g = gid[i];
  if (i == 0) {
    for (int x = 0; x <= g; ++x) gb[x] = 0;
  } else {
    int pg = gid[i - 1];
    for (int x = pg + 1; x <= g; ++x) gb[x] = i;
  }
  if (i == n - 1) {
    for (int x = g + 1; x <= GG; ++x) gb[x] = n;
  }
}

// ---------------------------------------------------------------- edge scores (bf16 in, CSR-ordered out)
__global__ __launch_bounds__(256) void k_edge_score(
    const __hip_bfloat16* __restrict__ Q, const __hip_bfloat16* __restrict__ Kb,
    const int* __restrict__ src, const int* __restrict__ dst,
    const int* __restrict__ epos, float* __restrict__ sedge, int ne) {
  int idx = blockIdx.x * blockDim.x + threadIdx.x;
  if (idx >= ne * HH) return;
  int e = idx >> 3;
  int hh = idx & 7;
  const bf16x8* kr = (const bf16x8*)(Kb + (size_t)src[e] * DD + hh * DHH);
  const bf16x8* qr = (const bf16x8*)(Q + (size_t)dst[e] * DD + hh * DHH);
  float dot = 0.f;
#pragma unroll
  for (int c = 0; c < 4; ++c) {
    bf16x8 a = kr[c], b = qr[c];
#pragma unroll
    for (int u = 0; u < 8; ++u) dot += b2f(a[u]) * b2f(b[u]);
  }
  float x = dot * 0.17677669529663687f;  // 1/sqrt(32)
  x = fminf(fmaxf(x, -5.f), 5.f);
  sedge[(size_t)epos[e] * HH + hh] = expf(x);
}

// ---------------------------------------------------------------- segment softmax + p*V (max folded in)
__global__ __launch_bounds__(256) void k_aggregate(
    const int* __restrict__ indptr, const int* __restrict__ csr_src,
    const float* __restrict__ sedge,
    const __hip_bfloat16* __restrict__ V, __hip_bfloat16* __restrict__ attn) {
  int n = blockIdx.x;
  int t = threadIdx.x;
  int hh = t >> 5, lane = t & 31;
  int s0 = indptr[n], s1 = indptr[n + 1];
  float m = 0.f;  // s > 0 always, so 0 is a safe identity
  for (int j = s0 + lane; j < s1; j += 32)
    m = fmaxf(m, sedge[(size_t)j * HH + hh]);
#pragma unroll
  for (int o = 16; o > 0; o >>= 1) m = fmaxf(m, __shfl_xor(m, o, 32));
  float den = 0.f, acc = 0.f;
  for (int basei = s0; basei < s1; basei += 32) {
    int j = basei + lane;
    float p = 0.f;
    int srcv = 0;
    if (j < s1) {
      p = expf(sedge[(size_t)j * HH + hh] - m);
      srcv = csr_src[j];
    }
    den += p;
    int cnt = min(32, s1 - basei);
    for (int k = 0; k < cnt; ++k) {
      float pk = __shfl(p, k, 32);
      int srow = __shfl(srcv, k, 32);
      acc += pk * b2f(((const short*)V)[(size_t)srow * DD + hh * DHH + lane]);
    }
  }
#pragma unroll
  for (int o = 16; o > 0; o >>= 1) den += __shfl_xor(den, o, 32);
  attn[(size_t)n * DD + hh * DHH + lane] = __float2bfloat16(acc / (den > 0.f ? den : 1.f));
}

// ---------------------------------------------------------------- residual + LN (f32 + bf16 shadow)
__global__ __launch_bounds__(256) void k_ln(
    float* __restrict__ h, const float* __restrict__ add,
    const float* __restrict__ g, const float* __restrict__ b,
    __hip_bfloat16* __restrict__ hb, int n) {
  int row = blockIdx.x * 4 + (threadIdx.x >> 6);
  int lane = threadIdx.x & 63;
  if (row >= n) return;
  const size_t base = (size_t)row * DD;
  float x[4];
  float s = 0.f;
#pragma unroll
  for (int j = 0; j < 4; ++j) {
    int d = lane + j * 64;
    x[j] = h[base + d] + add[base + d];
    s += x[j];
  }
#pragma unroll
  for (int o = 32; o > 0; o >>= 1) s += __shfl_xor(s, o, 64);
  float mean = s * (1.f / 256.f);
  float vs = 0.f;
#pragma unroll
  for (int j = 0; j < 4; ++j) {
    float d = x[j] - mean;
    vs += d * d;
  }
#pragma unroll
  for (int o = 32; o > 0; o >>= 1) vs += __shfl_xor(vs, o, 64);
  float rs = rsqrtf(vs * (1.f / 256.f) + 1e-5f);
#pragma unroll
  for (int j = 0; j < 4; ++j) {
    int d = lane + j * 64;
    float v = g[d] * ((x[j] - mean) * rs) + b[d];
    h[base + d] = v;
    hb[base + d] = __float2bfloat16(v);
  }
}

// ---------------------------------------------------------------- readout: register-accumulated graph mean
__global__ __launch_bounds__(256) void k_gmean(
    const float* __restrict__ h, const int* __restrict__ gb,
    float* __restrict__ gsum) {
  int g = blockIdx.x, s = blockIdx.y;
  int t = threadIdx.x;
  int r0 = gb[g], r1 = gb[g + 1];
  int len = r1 - r0;
  int per = (len + RSPLITS - 1) / RSPLITS;
  int a = r0 + s * per;
  int b = min(r1, a + per);
  if (a >= b) return;
  float acc = 0.f;
  for (int r = a; r < b; ++r) acc += h[(size_t)r * DD + t];
  atomicAdd(&gsum[g * DD + t], acc);
}

__global__ void k_final(const float* __restrict__ gsum, const int* __restrict__ gb,
                        float* __restrict__ out) {
  int g = blockIdx.x, t = threadIdx.x;
  int len = gb[g + 1] - gb[g];
  out[g * DD + t] = gsum[g * DD + t] / (len > 0 ? (float)len : 1.f);
}

// ---------------------------------------------------------------- launch
extern "C" void kernel_launch(void* const* d_in, const int* in_sizes, int n_in,
                              void* d_out, int out_size, void* d_ws, size_t ws_size,
                              hipStream_t stream) {
  const float* feat = (const float*)d_in[0];
  const float* lap  = (const float*)d_in[1];
  const float* sign = (const float*)d_in[2];
  const int* srcs   = (const int*)d_in[3];
  const int* dsts   = (const int*)d_in[4];
  const int* gids   = (const int*)d_in[5];
  const float* Wh   = (const float*)d_in[6];
  const float* bh   = (const float*)d_in[7];
  const float* Wlp  = (const float*)d_in[8];
  const float* blp  = (const float*)d_in[9];
  const float* Wq   = (const float*)d_in[10];
  const float* Wk   = (const float*)d_in[11];
  const float* Wv   = (const float*)d_in[12];
  const float* Wo   = (const float*)d_in[13];
  const float* bo   = (const float*)d_in[14];
  const float* g1   = (const float*)d_in[15];
  const float* b1   = (const float*)d_in[16];
  const float* W1   = (const float*)d_in[17];
  const float* c1   = (const float*)d_in[18];
  const float* W2   = (const float*)d_in[19];
  const float* c2   = (const float*)d_in[20];
  const float* g2   = (const float*)d_in[21];
  const float* b2   = (const float*)d_in[22];

  char* base = (char*)d_ws;
  size_t off = 0;
  auto take = [&](size_t bytes) -> void* {
    void* p = base + off;
    off += (bytes + 255) & ~(size_t)255;
    return p;
  };
  float* h      = (float*)take((size_t)NN * DD * 4);
  __hip_bfloat16* hb = (__hip_bfloat16*)take((size_t)NN * DD * 2);
  __hip_bfloat16* Qb = (__hip_bfloat16*)take((size_t)NN * DD * 2);
  __hip_bfloat16* Kb = (__hip_bfloat16*)take((size_t)NN * DD * 2);
  __hip_bfloat16* Vb = (__hip_bfloat16*)take((size_t)NN * DD * 2);
  float* tmp    = (float*)take((size_t)NN * DD * 4);
  float* sedge  = (float*)take((size_t)EE * HH * 4);
  __hip_bfloat16* t1b = (__hip_bfloat16*)take((size_t)NN * DFF * 2);
  __hip_bfloat16* Wqt = (__hip_bfloat16*)take((size_t)LLAYERS * DD * DD * 2);
  __hip_bfloat16* Wkt = (__hip_bfloat16*)take((size_t)LLAYERS * DD * DD * 2);
  __hip_bfloat16* Wvt = (__hip_bfloat16*)take((size_t)LLAYERS * DD * DD * 2);
  __hip_bfloat16* Wot = (__hip_bfloat16*)take((size_t)LLAYERS * DD * DD * 2);
  __hip_bfloat16* W1t = (__hip_bfloat16*)take((size_t)LLAYERS * DD * DFF * 2);
  __hip_bfloat16* W2t = (__hip_bfloat16*)take((size_t)LLAYERS * DFF * DD * 2);
  int* deg     = (int*)take((size_t)NN * 4);
  int* ex      = (int*)take((size_t)NN * 4);
  int* bsum    = (int*)take(256 * 4);
  int* boff    = (int*)take(256 * 4);
  int* indptr  = (int*)take((size_t)(NN + 1) * 4);
  int* cursor  = (int*)take((size_t)NN * 4);
  int* csr_src = (int*)take((size_t)EE * 4);
  int* epos    = (int*)take((size_t)EE * 4);
  int* gb      = (int*)take((size_t)(GG + 1) * 4);
  float* gsum  = (float*)take((size_t)GG * DD * 4);
  __hip_bfloat16* attnb = Qb;  // Q dead after edge scores

  const int NB = (NN + 255) / 256;

  // weight convert+transpose
  k_wt<<<dim3(DD / 32, DD / 32, LLAYERS), 256, 0, stream>>>(Wq, Wqt, DD, DD);
  k_wt<<<dim3(DD / 32, DD / 32, LLAYERS), 256, 0, stream>>>(Wk, Wkt, DD, DD);
  k_wt<<<dim3(DD / 32, DD / 32, LLAYERS), 256, 0, stream>>>(Wv, Wvt, DD, DD);
  k_wt<<<dim3(DD / 32, DD / 32, LLAYERS), 256, 0, stream>>>(Wo, Wot, DD, DD);
  k_wt<<<dim3(DFF / 32, DD / 32, LLAYERS), 256, 0, stream>>>(W1, W1t, DD, DFF);
  k_wt<<<dim3(DD / 32, DFF / 32, LLAYERS), 256, 0, stream>>>(W2, W2t, DFF, DD);

  // CSR by dst + graph bounds
  hipMemsetAsync(deg, 0, (size_t)NN * 4, stream);
  k_hist<<<(EE + 255) / 256, 256, 0, stream>>>(dsts, deg, EE);
  k_scan_block<<<NB, 256, 0, stream>>>(deg, ex, bsum, NN);
  k_scan_top<<<1, 256, 0, stream>>>(bsum, boff, NB);
  k_finish_indptr<<<NB, 256, 0, stream>>>(ex, boff, indptr, cursor, NN, EE);
  k_fill<<<(EE + 255) / 256, 256, 0, stream>>>(dsts, srcs, cursor, csr_src, epos, EE);
  k_bounds<<<NB, 256, 0, stream>>>(gids, gb, NN);

  // embedding
  k_embed<<<NN, 256, 0, stream>>>(feat, lap, sign, Wh, bh, Wlp, blp, h, hb);

  const int MB = (NN + 127) / 128;  // 157
  dim3 gQKV(MB, DD / 128, 3);
  dim3 gD(MB, DD / 128, 1);
  dim3 gF(MB, DFF / 128, 1);

  for (int l = 0; l < LLAYERS; ++l) {
    const __hip_bfloat16* Wqt_l = Wqt + (size_t)l * DD * DD;
    const __hip_bfloat16* Wkt_l = Wkt + (size_t)l * DD * DD;
    const __hip_bfloat16* Wvt_l = Wvt + (size_t)l * DD * DD;
    const __hip_bfloat16* Wot_l = Wot + (size_t)l * DD * DD;
    const __hip_bfloat16* W1t_l = W1t + (size_t)l * DD * DFF;
    const __hip_bfloat16* W2t_l = W2t + (size_t)l * DFF * DD;
    const float* bo_l = bo + (size_t)l * DD;
    const float* g1_l = g1 + (size_t)l * DD;
    const float* b1_l = b1 + (size_t)l * DD;
    const float* c1_l = c1 + (size_t)l * DFF;
    const float* c2_l = c2 + (size_t)l * DD;
    const float* g2_l = g2 + (size_t)l * DD;
    const float* b2_l = b2 + (size_t)l * DD;

    gemm_mfma<false, false, true><<<gQKV, 256, 0, stream>>>(
        hb, Wqt_l, Wkt_l, Wvt_l, nullptr, Qb, Kb, Vb, NN, DD, DD);

    k_edge_score<<<((size_t)EE * HH + 255) / 256, 256, 0, stream>>>(
        Qb, Kb, srcs, dsts, epos, sedge, EE);
    k_aggregate<<<NN, 256, 0, stream>>>(indptr, csr_src, sedge, Vb, attnb);

    gemm_mfma<true, false, false><<<gD, 256, 0, stream>>>(
        attnb, Wot_l, Wot_l, Wot_l, bo_l, tmp, tmp, tmp, NN, DD, DD);
    k_ln<<<NN / 4, 256, 0, stream>>>(h, tmp, g1_l, b1_l, hb, NN);

    gemm_mfma<true, true, true><<<gF, 256, 0, stream>>>(
        hb, W1t_l, W1t_l, W1t_l, c1_l, t1b, t1b, t1b, NN, DFF, DD);
    gemm_mfma<true, false, false><<<gD, 256, 0, stream>>>(
        t1b, W2t_l, W2t_l, W2t_l, c2_l, tmp, tmp, tmp, NN, DD, DFF);
    k_ln<<<NN / 4, 256, 0, stream>>>(h, tmp, g2_l, b2_l, hb, NN);
  }

  hipMemsetAsync(gsum, 0, (size_t)GG * DD * 4, stream);
  k_gmean<<<dim3(GG, RSPLITS), 256, 0, stream>>>(h, gb, gsum);
  k_final<<<GG, 256, 0, stream>>>(gsum, gb, (float*)d_out);
}

// Round 5
// 492.565 us; speedup vs baseline: 3.1234x; 1.2395x over previous
//
#include <hip/hip_runtime.h>
#include <hip/hip_bf16.h>

#define NN   20000
#define EE   320000
#define GG   16
#define DD   256
#define HH   8
#define DHH  32
#define LLAYERS 2
#define DFF  512
#define DIN  32
#define DLAP 16
#define RSPLITS 16

typedef __attribute__((ext_vector_type(8))) short bf16x8;
typedef __attribute__((ext_vector_type(4))) float f32x4;

__device__ __forceinline__ void gld_lds16(const void* g, void* l) {
  __builtin_amdgcn_global_load_lds((const __attribute__((address_space(1))) uint32_t*)g,
                                   (__attribute__((address_space(3))) uint32_t*)l, 16, 0, 0);
}

__device__ __forceinline__ float b2f(unsigned short s) {
  union { unsigned int i; float f; } u;
  u.i = ((unsigned int)s) << 16;
  return u.f;
}

__device__ __forceinline__ unsigned short f2bu(float f) {
  __hip_bfloat16 b = __float2bfloat16(f);
  return *(unsigned short*)&b;
}

// ---------------------------------------------------------------- embed (f32 + bf16 shadow)
__global__ __launch_bounds__(256) void k_embed(
    const float* __restrict__ feat, const float* __restrict__ lap,
    const float* __restrict__ sign, const float* __restrict__ Wh,
    const float* __restrict__ bh, const float* __restrict__ Wlp,
    const float* __restrict__ blp, float* __restrict__ h,
    __hip_bfloat16* __restrict__ hb) {
  int n = blockIdx.x;
  int d = threadIdx.x;
  float acc = bh[d] + blp[d];
  const float* frow = feat + (size_t)n * DIN;
  const float* lrow = lap + (size_t)n * DLAP;
#pragma unroll
  for (int k = 0; k < DIN; ++k) acc += frow[k] * Wh[k * DD + d];
#pragma unroll
  for (int k = 0; k < DLAP; ++k) acc += (lrow[k] * sign[k]) * Wlp[k * DD + d];
  h[(size_t)n * DD + d] = acc;
  hb[(size_t)n * DD + d] = __float2bfloat16(acc);
}

// ---------------------------------------------------------------- weight transpose+convert
__global__ __launch_bounds__(256) void k_wt(
    const float* __restrict__ in, __hip_bfloat16* __restrict__ out, int K, int N) {
  __shared__ float tile[32][33];
  const float* inl = in + (size_t)blockIdx.z * K * N;
  __hip_bfloat16* outl = out + (size_t)blockIdx.z * N * K;
  int bx = blockIdx.x;
  int by = blockIdx.y;
  int tx = threadIdx.x & 31, ty = threadIdx.x >> 5;
#pragma unroll
  for (int i = 0; i < 32; i += 8)
    tile[ty + i][tx] = inl[(size_t)(by * 32 + ty + i) * N + bx * 32 + tx];
  __syncthreads();
#pragma unroll
  for (int i = 0; i < 32; i += 8)
    outl[(size_t)(bx * 32 + ty + i) * K + by * 32 + tx] = __float2bfloat16(tile[tx][ty + i]);
}

// ---------------------------------------------------------------- MFMA bf16 GEMM (128x128, BK=32)
template <bool BIAS, bool RELU, bool OUTBF16>
__global__ __launch_bounds__(256) void gemm_mfma(
    const __hip_bfloat16* __restrict__ A,
    const __hip_bfloat16* __restrict__ Bt0, const __hip_bfloat16* __restrict__ Bt1,
    const __hip_bfloat16* __restrict__ Bt2,
    const float* __restrict__ bias,
    void* __restrict__ C0, void* __restrict__ C1, void* __restrict__ C2,
    int M, int Ncols, int K) {
  const __hip_bfloat16* Bt = (blockIdx.z == 0) ? Bt0 : (blockIdx.z == 1) ? Bt1 : Bt2;
  void* Cout = (blockIdx.z == 0) ? C0 : (blockIdx.z == 1) ? C1 : C2;

  __shared__ short lA[2][4][128][8];
  __shared__ short lB[2][4][128][8];

  const int t = threadIdx.x;
  const int lane = t & 63, w = t >> 6;
  const int bm = blockIdx.x * 128, bn = blockIdx.y * 128;
  const int wr = w >> 1, wc = w & 1;
  const int fr = lane & 15, fg = lane >> 4;

  f32x4 acc[4][4] = {};

  auto stage = [&](int buf, int kt) {
    const int k0 = kt * 32;
#pragma unroll
    for (int it = 0; it < 2; ++it) {
      const int cbase = it * 256 + w * 64;
      const int c = cbase + lane;
      const int g = c >> 7, r = c & 127;
      int arow = bm + r;
      if (arow >= M) arow = M - 1;
      gld_lds16(A + (size_t)arow * K + k0 + g * 8,
                (short*)lA + ((size_t)buf * 4 * 128 + cbase) * 8);
      gld_lds16(Bt + (size_t)(bn + r) * K + k0 + g * 8,
                (short*)lB + ((size_t)buf * 4 * 128 + cbase) * 8);
    }
  };

  const int nt = K >> 5;
  stage(0, 0);
  for (int kt = 0; kt < nt; ++kt) {
    const int buf = kt & 1;
    __syncthreads();
    if (kt + 1 < nt) stage(buf ^ 1, kt + 1);
    bf16x8 af[4], bfr[4];
#pragma unroll
    for (int i = 0; i < 4; ++i)
      af[i] = *(const bf16x8*)&lA[buf][fg][wr * 64 + i * 16 + fr][0];
#pragma unroll
    for (int j = 0; j < 4; ++j)
      bfr[j] = *(const bf16x8*)&lB[buf][fg][wc * 64 + j * 16 + fr][0];
#pragma unroll
    for (int i = 0; i < 4; ++i)
#pragma unroll
      for (int j = 0; j < 4; ++j)
        acc[i][j] = __builtin_amdgcn_mfma_f32_16x16x32_bf16(af[i], bfr[j], acc[i][j], 0, 0, 0);
  }

#pragma unroll
  for (int i = 0; i < 4; ++i) {
    const int row0 = bm + wr * 64 + i * 16 + fg * 4;
#pragma unroll
    for (int j = 0; j < 4; ++j) {
      const int col = bn + wc * 64 + j * 16 + fr;
      float bv = BIAS ? bias[col] : 0.f;
#pragma unroll
      for (int r = 0; r < 4; ++r) {
        const int row = row0 + r;
        if (row >= M) continue;
        float v = acc[i][j][r] + bv;
        if (RELU) v = fmaxf(v, 0.f);
        if (OUTBF16)
          ((__hip_bfloat16*)Cout)[(size_t)row * Ncols + col] = __float2bfloat16(v);
        else
          ((float*)Cout)[(size_t)row * Ncols + col] = v;
      }
    }
  }
}

// ---------------------------------------------------------------- CSR build
__global__ void k_hist(const int* __restrict__ dst, int* __restrict__ deg, int n) {
  int i = blockIdx.x * blockDim.x + threadIdx.x;
  if (i < n) atomicAdd(&deg[dst[i]], 1);
}

__global__ __launch_bounds__(256) void k_scan_block(
    const int* __restrict__ in, int* __restrict__ ex, int* __restrict__ bsum, int n) {
  __shared__ int sm[256];
  int t = threadIdx.x;
  int i = blockIdx.x * 256 + t;
  int v = (i < n) ? in[i] : 0;
  sm[t] = v;
  __syncthreads();
  for (int o = 1; o < 256; o <<= 1) {
    int x = (t >= o) ? sm[t - o] : 0;
    __syncthreads();
    sm[t] += x;
    __syncthreads();
  }
  if (i < n) ex[i] = sm[t] - v;
  if (t == 255) bsum[blockIdx.x] = sm[255];
}

__global__ __launch_bounds__(256) void k_scan_top(
    const int* __restrict__ bsum, int* __restrict__ boff, int nb) {
  __shared__ int sm[256];
  int t = threadIdx.x;
  int v = (t < nb) ? bsum[t] : 0;
  sm[t] = v;
  __syncthreads();
  for (int o = 1; o < 256; o <<= 1) {
    int x = (t >= o) ? sm[t - o] : 0;
    __syncthreads();
    sm[t] += x;
    __syncthreads();
  }
  if (t < nb) boff[t] = sm[t] - v;
}

__global__ void k_finish_indptr(const int* __restrict__ ex, const int* __restrict__ boff,
                                int* __restrict__ indptr, int* __restrict__ cursor,
                                int n, int total) {
  int i = blockIdx.x * 256 + threadIdx.x;
  if (i < n) {
    int v = ex[i] + boff[i >> 8];
    indptr[i] = v;
    cursor[i] = v;
  }
  if (i == 0) indptr[n] = total;
}

// fill CSR: csr_src[pos]=src[e], csr_dst[pos]=dst[e]
__global__ void k_fill(const int* __restrict__ dst, const int* __restrict__ src,
                       int* __restrict__ cursor, int* __restrict__ csr_src,
                       int* __restrict__ csr_dst, int n) {
  int i = blockIdx.x * blockDim.x + threadIdx.x;
  if (i < n) {
    int d = dst[i];
    int pos = atomicAdd(&cursor[d], 1);
    csr_src[pos] = src[i];
    csr_dst[pos] = d;
  }
}

// graph boundaries from sorted gids
__global__ void k_bounds(const int* __restrict__ gid, int* __restrict__ gb, int n) {
  int i = blockIdx.x * blockDim.x + threadIdx.x;
  if (i >= n) return;
  int g = gid[i];
  if (i == 0) {
    for (int x = 0; x <= g; ++x) gb[x] = 0;
  } else {
    int pg = gid[i - 1];
    for (int x = pg + 1; x <= g; ++x) gb[x] = i;
  }
  if (i == n - 1) {
    for (int x = g + 1; x <= GG; ++x) gb[x] = n;
  }
}

// ---------------------------------------------------------------- edge scores (CSR-driven: coalesced writes, L1-friendly Q)
__global__ __launch_bounds__(256) void k_edge_score(
    const __hip_bfloat16* __restrict__ Q, const __hip_bfloat16* __restrict__ Kb,
    const int* __restrict__ csr_src, const int* __restrict__ csr_dst,
    float* __restrict__ sedge, int ne) {
  int idx = blockIdx.x * blockDim.x + threadIdx.x;
  if (idx >= ne * HH) return;
  int pos = idx >> 3;
  int hh = idx & 7;
  const bf16x8* kr = (const bf16x8*)(Kb + (size_t)csr_src[pos] * DD + hh * DHH);
  const bf16x8* qr = (const bf16x8*)(Q + (size_t)csr_dst[pos] * DD + hh * DHH);
  float dot = 0.f;
#pragma unroll
  for (int c = 0; c < 4; ++c) {
    bf16x8 a = kr[c], b = qr[c];
#pragma unroll
    for (int u = 0; u < 8; ++u) dot += b2f((unsigned short)a[u]) * b2f((unsigned short)b[u]);
  }
  float x = dot * 0.17677669529663687f;  // 1/sqrt(32)
  x = fminf(fmaxf(x, -5.f), 5.f);
  sedge[idx] = expf(x);
}

// ---------------------------------------------------------------- aggregate: one wave per node, lane owns 4 dims
__global__ __launch_bounds__(256) void k_aggregate(
    const int* __restrict__ indptr, const int* __restrict__ csr_src,
    const float* __restrict__ sedge,
    const __hip_bfloat16* __restrict__ V, __hip_bfloat16* __restrict__ attn) {
  int n = blockIdx.x * 4 + (threadIdx.x >> 6);
  if (n >= NN) return;
  int lane = threadIdx.x & 63;
  int hh = lane >> 3;             // head of this lane's 4 dims
  int doff = lane * 4;            // dims [doff, doff+4)
  int s0 = indptr[n], s1 = indptr[n + 1];

  // pass 1: segment max (32B coalesced broadcast per edge)
  float m = 0.f;  // all s > 0
#pragma unroll 4
  for (int j = s0; j < s1; ++j) m = fmaxf(m, sedge[(size_t)j * HH + hh]);

  // pass 2: den + p*V (512B coalesced V row per edge)
  float den = 0.f;
  float a0 = 0.f, a1 = 0.f, a2 = 0.f, a3 = 0.f;
#pragma unroll 2
  for (int j = s0; j < s1; ++j) {
    float p = expf(sedge[(size_t)j * HH + hh] - m);
    den += p;
    int srow = csr_src[j];
    ushort4 v = *(const ushort4*)((const unsigned short*)V + (size_t)srow * DD + doff);
    a0 += p * b2f(v.x);
    a1 += p * b2f(v.y);
    a2 += p * b2f(v.z);
    a3 += p * b2f(v.w);
  }
  float inv = 1.f / (den > 0.f ? den : 1.f);
  ushort4 o;
  o.x = f2bu(a0 * inv);
  o.y = f2bu(a1 * inv);
  o.z = f2bu(a2 * inv);
  o.w = f2bu(a3 * inv);
  *(ushort4*)((unsigned short*)attn + (size_t)n * DD + doff) = o;
}

// ---------------------------------------------------------------- residual + LN (f32 + bf16 shadow)
__global__ __launch_bounds__(256) void k_ln(
    float* __restrict__ h, const float* __restrict__ add,
    const float* __restrict__ g, const float* __restrict__ b,
    __hip_bfloat16* __restrict__ hb, int n) {
  int row = blockIdx.x * 4 + (threadIdx.x >> 6);
  int lane = threadIdx.x & 63;
  if (row >= n) return;
  const size_t base = (size_t)row * DD;
  float x[4];
  float s = 0.f;
#pragma unroll
  for (int j = 0; j < 4; ++j) {
    int d = lane + j * 64;
    x[j] = h[base + d] + add[base + d];
    s += x[j];
  }
#pragma unroll
  for (int o = 32; o > 0; o >>= 1) s += __shfl_xor(s, o, 64);
  float mean = s * (1.f / 256.f);
  float vs = 0.f;
#pragma unroll
  for (int j = 0; j < 4; ++j) {
    float d = x[j] - mean;
    vs += d * d;
  }
#pragma unroll
  for (int o = 32; o > 0; o >>= 1) vs += __shfl_xor(vs, o, 64);
  float rs = rsqrtf(vs * (1.f / 256.f) + 1e-5f);
#pragma unroll
  for (int j = 0; j < 4; ++j) {
    int d = lane + j * 64;
    float v = g[d] * ((x[j] - mean) * rs) + b[d];
    h[base + d] = v;
    hb[base + d] = __float2bfloat16(v);
  }
}

// ---------------------------------------------------------------- readout
__global__ __launch_bounds__(256) void k_gmean(
    const float* __restrict__ h, const int* __restrict__ gb,
    float* __restrict__ gsum) {
  int g = blockIdx.x, s = blockIdx.y;
  int t = threadIdx.x;
  int r0 = gb[g], r1 = gb[g + 1];
  int len = r1 - r0;
  int per = (len + RSPLITS - 1) / RSPLITS;
  int a = r0 + s * per;
  int b = min(r1, a + per);
  if (a >= b) return;
  float acc = 0.f;
  for (int r = a; r < b; ++r) acc += h[(size_t)r * DD + t];
  atomicAdd(&gsum[g * DD + t], acc);
}

__global__ void k_final(const float* __restrict__ gsum, const int* __restrict__ gb,
                        float* __restrict__ out) {
  int g = blockIdx.x, t = threadIdx.x;
  int len = gb[g + 1] - gb[g];
  out[g * DD + t] = gsum[g * DD + t] / (len > 0 ? (float)len : 1.f);
}

// ---------------------------------------------------------------- launch
extern "C" void kernel_launch(void* const* d_in, const int* in_sizes, int n_in,
                              void* d_out, int out_size, void* d_ws, size_t ws_size,
                              hipStream_t stream) {
  const float* feat = (const float*)d_in[0];
  const float* lap  = (const float*)d_in[1];
  const float* sign = (const float*)d_in[2];
  const int* srcs   = (const int*)d_in[3];
  const int* dsts   = (const int*)d_in[4];
  const int* gids   = (const int*)d_in[5];
  const float* Wh   = (const float*)d_in[6];
  const float* bh   = (const float*)d_in[7];
  const float* Wlp  = (const float*)d_in[8];
  const float* blp  = (const float*)d_in[9];
  const float* Wq   = (const float*)d_in[10];
  const float* Wk   = (const float*)d_in[11];
  const float* Wv   = (const float*)d_in[12];
  const float* Wo   = (const float*)d_in[13];
  const float* bo   = (const float*)d_in[14];
  const float* g1   = (const float*)d_in[15];
  const float* b1   = (const float*)d_in[16];
  const float* W1   = (const float*)d_in[17];
  const float* c1   = (const float*)d_in[18];
  const float* W2   = (const float*)d_in[19];
  const float* c2   = (const float*)d_in[20];
  const float* g2   = (const float*)d_in[21];
  const float* b2   = (const float*)d_in[22];

  char* base = (char*)d_ws;
  size_t off = 0;
  auto take = [&](size_t bytes) -> void* {
    void* p = base + off;
    off += (bytes + 255) & ~(size_t)255;
    return p;
  };
  float* h      = (float*)take((size_t)NN * DD * 4);
  __hip_bfloat16* hb = (__hip_bfloat16*)take((size_t)NN * DD * 2);
  __hip_bfloat16* Qb = (__hip_bfloat16*)take((size_t)NN * DD * 2);
  __hip_bfloat16* Kb = (__hip_bfloat16*)take((size_t)NN * DD * 2);
  __hip_bfloat16* Vb = (__hip_bfloat16*)take((size_t)NN * DD * 2);
  float* tmp    = (float*)take((size_t)NN * DD * 4);
  float* sedge  = (float*)take((size_t)EE * HH * 4);
  __hip_bfloat16* t1b = (__hip_bfloat16*)take((size_t)NN * DFF * 2);
  __hip_bfloat16* Wqt = (__hip_bfloat16*)take((size_t)LLAYERS * DD * DD * 2);
  __hip_bfloat16* Wkt = (__hip_bfloat16*)take((size_t)LLAYERS * DD * DD * 2);
  __hip_bfloat16* Wvt = (__hip_bfloat16*)take((size_t)LLAYERS * DD * DD * 2);
  __hip_bfloat16* Wot = (__hip_bfloat16*)take((size_t)LLAYERS * DD * DD * 2);
  __hip_bfloat16* W1t = (__hip_bfloat16*)take((size_t)LLAYERS * DD * DFF * 2);
  __hip_bfloat16* W2t = (__hip_bfloat16*)take((size_t)LLAYERS * DFF * DD * 2);
  int* deg     = (int*)take((size_t)NN * 4);
  int* ex      = (int*)take((size_t)NN * 4);
  int* bsum    = (int*)take(256 * 4);
  int* boff    = (int*)take(256 * 4);
  int* indptr  = (int*)take((size_t)(NN + 1) * 4);
  int* cursor  = (int*)take((size_t)NN * 4);
  int* csr_src = (int*)take((size_t)EE * 4);
  int* csr_dst = (int*)take((size_t)EE * 4);
  int* gb      = (int*)take((size_t)(GG + 1) * 4);
  float* gsum  = (float*)take((size_t)GG * DD * 4);
  __hip_bfloat16* attnb = Qb;  // Q dead after edge scores

  const int NB = (NN + 255) / 256;

  // weight convert+transpose
  k_wt<<<dim3(DD / 32, DD / 32, LLAYERS), 256, 0, stream>>>(Wq, Wqt, DD, DD);
  k_wt<<<dim3(DD / 32, DD / 32, LLAYERS), 256, 0, stream>>>(Wk, Wkt, DD, DD);
  k_wt<<<dim3(DD / 32, DD / 32, LLAYERS), 256, 0, stream>>>(Wv, Wvt, DD, DD);
  k_wt<<<dim3(DD / 32, DD / 32, LLAYERS), 256, 0, stream>>>(Wo, Wot, DD, DD);
  k_wt<<<dim3(DFF / 32, DD / 32, LLAYERS), 256, 0, stream>>>(W1, W1t, DD, DFF);
  k_wt<<<dim3(DD / 32, DFF / 32, LLAYERS), 256, 0, stream>>>(W2, W2t, DFF, DD);

  // CSR by dst + graph bounds
  hipMemsetAsync(deg, 0, (size_t)NN * 4, stream);
  k_hist<<<(EE + 255) / 256, 256, 0, stream>>>(dsts, deg, EE);
  k_scan_block<<<NB, 256, 0, stream>>>(deg, ex, bsum, NN);
  k_scan_top<<<1, 256, 0, stream>>>(bsum, boff, NB);
  k_finish_indptr<<<NB, 256, 0, stream>>>(ex, boff, indptr, cursor, NN, EE);
  k_fill<<<(EE + 255) / 256, 256, 0, stream>>>(dsts, srcs, cursor, csr_src, csr_dst, EE);
  k_bounds<<<NB, 256, 0, stream>>>(gids, gb, NN);

  // embedding
  k_embed<<<NN, 256, 0, stream>>>(feat, lap, sign, Wh, bh, Wlp, blp, h, hb);

  const int MB = (NN + 127) / 128;  // 157
  dim3 gQKV(MB, DD / 128, 3);
  dim3 gD(MB, DD / 128, 1);
  dim3 gF(MB, DFF / 128, 1);

  for (int l = 0; l < LLAYERS; ++l) {
    const __hip_bfloat16* Wqt_l = Wqt + (size_t)l * DD * DD;
    const __hip_bfloat16* Wkt_l = Wkt + (size_t)l * DD * DD;
    const __hip_bfloat16* Wvt_l = Wvt + (size_t)l * DD * DD;
    const __hip_bfloat16* Wot_l = Wot + (size_t)l * DD * DD;
    const __hip_bfloat16* W1t_l = W1t + (size_t)l * DD * DFF;
    const __hip_bfloat16* W2t_l = W2t + (size_t)l * DFF * DD;
    const float* bo_l = bo + (size_t)l * DD;
    const float* g1_l = g1 + (size_t)l * DD;
    const float* b1_l = b1 + (size_t)l * DD;
    const float* c1_l = c1 + (size_t)l * DFF;
    const float* c2_l = c2 + (size_t)l * DD;
    const float* g2_l = g2 + (size_t)l * DD;
    const float* b2_l = b2 + (size_t)l * DD;

    gemm_mfma<false, false, true><<<gQKV, 256, 0, stream>>>(
        hb, Wqt_l, Wkt_l, Wvt_l, nullptr, Qb, Kb, Vb, NN, DD, DD);

    k_edge_score<<<((size_t)EE * HH + 255) / 256, 256, 0, stream>>>(
        Qb, Kb, csr_src, csr_dst, sedge, EE);
    k_aggregate<<<(NN + 3) / 4, 256, 0, stream>>>(indptr, csr_src, sedge, Vb, attnb);

    gemm_mfma<true, false, false><<<gD, 256, 0, stream>>>(
        attnb, Wot_l, Wot_l, Wot_l, bo_l, tmp, tmp, tmp, NN, DD, DD);
    k_ln<<<NN / 4, 256, 0, stream>>>(h, tmp, g1_l, b1_l, hb, NN);

    gemm_mfma<true, true, true><<<gF, 256, 0, stream>>>(
        hb, W1t_l, W1t_l, W1t_l, c1_l, t1b, t1b, t1b, NN, DFF, DD);
    gemm_mfma<true, false, false><<<gD, 256, 0, stream>>>(
        t1b, W2t_l, W2t_l, W2t_l, c2_l, tmp, tmp, tmp, NN, DD, DFF);
    k_ln<<<NN / 4, 256, 0, stream>>>(h, tmp, g2_l, b2_l, hb, NN);
  }

  hipMemsetAsync(gsum, 0, (size_t)GG * DD * 4, stream);
  k_gmean<<<dim3(GG, RSPLITS), 256, 0, stream>>>(h, gb, gsum);
  k_final<<<GG, 256, 0, stream>>>(gsum, gb, (float*)d_out);
}